// Round 7
// baseline (595.955 us; speedup 1.0000x reference)
//
#include <hip/hip_runtime.h>
#include <math.h>

// ---------------------------------------------------------------------------
// TopoGAT: 2-layer GAT on MI355X.
// R2: agg kernels unrolled x8 (8 outstanding row gathers/wave).
// R3: CSR build via two-level binning (write-locality; ~1x writeback).
// R5: gather tables h1/g stored in bf16 (halves random-gather fabric bytes).
// R6: xform kernels re-split: 4 (resp 2) threads per node, 16 (resp 20)
//     columns each. Fixes R4/R5 thread=node structure which was GRID-limited
//     (391 blocks -> 17% occupancy) and SMEM-latency-bound (1 FMA per
//     s_loaded W value). W now per-lane float4 VMEM (L1-hot), grid 1564
//     blocks, ~45 VGPR -> no spills.
// ---------------------------------------------------------------------------

#define NBUK_MAX 512
#define BIN_CHUNK 4096

typedef unsigned short ushort_t;

__device__ inline unsigned int f2bf(float f) {  // RNE fp32->bf16
    unsigned int u = __float_as_uint(f);
    u += 0x7FFFu + ((u >> 16) & 1u);
    return u >> 16;
}
__device__ inline float bf2f(ushort_t b) {
    return __uint_as_float((unsigned int)b << 16);
}

__device__ inline int wave_incl_scan(int v, int lane) {
    #pragma unroll
    for (int ofs = 1; ofs < 64; ofs <<= 1) {
        int t = __shfl_up(v, ofs);
        if (lane >= ofs) v += t;
    }
    return v;
}

// Bucket histogram (bucket = dst>>8), LDS-aggregated.
__global__ __launch_bounds__(256) void k_bhist(const int* __restrict__ dst,
                                               int* __restrict__ bucketCnt,
                                               int E, int NBUK) {
    __shared__ int h[NBUK_MAX];
    int tid = threadIdx.x;
    for (int i = tid; i < NBUK; i += 256) h[i] = 0;
    __syncthreads();
    for (int i = blockIdx.x * 256 + tid; i < E; i += gridDim.x * 256)
        atomicAdd(&h[dst[i] >> 8], 1);
    __syncthreads();
    for (int i = tid; i < NBUK; i += 256) {
        int c = h[i];
        if (c) atomicAdd(&bucketCnt[i], c);
    }
}

// One-wave exclusive scan of bucket counts -> bucketOff, gCursor.
__global__ void k_bscan(const int* __restrict__ bucketCnt,
                        int* __restrict__ bucketOff, int* __restrict__ gCursor,
                        int* __restrict__ rowptr, int N, int E, int NBUK) {
    int lane = threadIdx.x & 63;
    int running = 0;
    for (int base = 0; base < NBUK; base += 64) {
        int idx = base + lane;
        int v = (idx < NBUK) ? bucketCnt[idx] : 0;
        int incl = wave_incl_scan(v, lane);
        int excl = running + incl - v;
        if (idx < NBUK) { bucketOff[idx] = excl; gCursor[idx] = excl; }
        running += __shfl(incl, 63);
    }
    if (lane == 0) { bucketOff[NBUK] = running; rowptr[N] = E; }
}

// Bin edges into bucket-contiguous tmp. One global atomic per (block,bucket);
// packed word = (src<<8) | (dst&255).
__global__ __launch_bounds__(256) void k_bin(const int* __restrict__ src,
                                             const int* __restrict__ dst,
                                             int* __restrict__ gCursor,
                                             unsigned int* __restrict__ tmp,
                                             int E, int NBUK) {
    __shared__ int lcnt[NBUK_MAX];
    __shared__ int lcur[NBUK_MAX];
    int tid = threadIdx.x;
    int base = blockIdx.x * BIN_CHUNK;
    for (int i = tid; i < NBUK; i += 256) lcnt[i] = 0;
    __syncthreads();
    #pragma unroll
    for (int k = 0; k < BIN_CHUNK / 256; k++) {
        int i = base + tid + k * 256;
        if (i < E) atomicAdd(&lcnt[dst[i] >> 8], 1);
    }
    __syncthreads();
    for (int b = tid; b < NBUK; b += 256) {
        int c = lcnt[b];
        lcur[b] = c ? atomicAdd(&gCursor[b], c) : 0;
    }
    __syncthreads();
    #pragma unroll
    for (int k = 0; k < BIN_CHUNK / 256; k++) {
        int i = base + tid + k * 256;
        if (i < E) {
            int d = dst[i];
            int p = atomicAdd(&lcur[d >> 8], 1);
            tmp[p] = ((unsigned int)src[i] << 8) | (unsigned int)(d & 255);
        }
    }
}

// Exact CSR fill within a bucket; csr writes confined to block-owned window.
__global__ __launch_bounds__(256) void k_fill2(const unsigned int* __restrict__ tmp,
                                               const int* __restrict__ bucketOff,
                                               int* __restrict__ rowptr,
                                               int* __restrict__ csr, int N) {
    __shared__ int cnt[256];
    __shared__ int cur[256];
    __shared__ int wsum[4];
    int b = blockIdx.x, tid = threadIdx.x;
    int lane = tid & 63, wv = tid >> 6;
    int e0 = bucketOff[b], e1 = bucketOff[b + 1];
    cnt[tid] = 0;
    __syncthreads();
    for (int i = e0 + tid; i < e1; i += 256)
        atomicAdd(&cnt[tmp[i] & 255u], 1);
    __syncthreads();
    int v = cnt[tid];
    int incl = wave_incl_scan(v, lane);
    if (lane == 63) wsum[wv] = incl;
    __syncthreads();
    int woff = 0;
    for (int i = 0; i < wv; i++) woff += wsum[i];
    int excl = woff + incl - v;
    int node = b * 256 + tid;
    if (node < N) rowptr[node] = e0 + excl;
    cur[tid] = e0 + excl;
    __syncthreads();
    for (int i = e0 + tid; i < e1; i += 256) {
        unsigned int t = tmp[i];
        int p = atomicAdd(&cur[t & 255u], 1);
        csr[p] = (int)(t >> 8);
    }
}

// h1b[n][64](bf16) = [x[n]|topo[n]] @ W1 ; as1/ad1 from fp32 accumulators.
// 4 threads per node; thread q owns columns [16q,16q+16) = heads 2q,2q+1.
__global__ __launch_bounds__(256) void k_xform1(const float* __restrict__ x,
                                                const float* __restrict__ topo,
                                                const float* __restrict__ W1,
                                                const float* __restrict__ asrc,
                                                const float* __restrict__ adst,
                                                ushort_t* __restrict__ h1b,
                                                float* __restrict__ as1,
                                                float* __restrict__ ad1, int N) {
    int t = blockIdx.x * 256 + threadIdx.x;
    int n = t >> 2, q = t & 3;
    if (n >= N) n = N - 1;  // tail: sibling threads write identical values
    const float4* xr = (const float4*)(x + (size_t)n * 128);
    float acc[16];
    #pragma unroll
    for (int c = 0; c < 16; c++) acc[c] = 0.f;
    float4 xv = xr[0];
    #pragma unroll 1
    for (int k4 = 0; k4 < 32; k4++) {
        float4 cur = xv;
        if (k4 < 31) xv = xr[k4 + 1];  // prefetch next x chunk
        float xs[4] = {cur.x, cur.y, cur.z, cur.w};
        #pragma unroll
        for (int r = 0; r < 4; r++) {
            const float4* Wr = (const float4*)(W1 + (size_t)(k4 * 4 + r) * 64) + q * 4;
            float4 w0 = Wr[0], w1 = Wr[1], w2 = Wr[2], w3 = Wr[3];
            float s = xs[r];
            acc[0]  = fmaf(s, w0.x, acc[0]);  acc[1]  = fmaf(s, w0.y, acc[1]);
            acc[2]  = fmaf(s, w0.z, acc[2]);  acc[3]  = fmaf(s, w0.w, acc[3]);
            acc[4]  = fmaf(s, w1.x, acc[4]);  acc[5]  = fmaf(s, w1.y, acc[5]);
            acc[6]  = fmaf(s, w1.z, acc[6]);  acc[7]  = fmaf(s, w1.w, acc[7]);
            acc[8]  = fmaf(s, w2.x, acc[8]);  acc[9]  = fmaf(s, w2.y, acc[9]);
            acc[10] = fmaf(s, w2.z, acc[10]); acc[11] = fmaf(s, w2.w, acc[11]);
            acc[12] = fmaf(s, w3.x, acc[12]); acc[13] = fmaf(s, w3.y, acc[13]);
            acc[14] = fmaf(s, w3.z, acc[14]); acc[15] = fmaf(s, w3.w, acc[15]);
        }
    }
    const float4* tr = (const float4*)(topo + (size_t)n * 8);
    float4 t0 = tr[0], t1 = tr[1];
    float tv[8] = {t0.x, t0.y, t0.z, t0.w, t1.x, t1.y, t1.z, t1.w};
    #pragma unroll
    for (int j = 0; j < 8; j++) {
        const float4* Wr = (const float4*)(W1 + (size_t)(128 + j) * 64) + q * 4;
        float4 w0 = Wr[0], w1 = Wr[1], w2 = Wr[2], w3 = Wr[3];
        float s = tv[j];
        acc[0]  = fmaf(s, w0.x, acc[0]);  acc[1]  = fmaf(s, w0.y, acc[1]);
        acc[2]  = fmaf(s, w0.z, acc[2]);  acc[3]  = fmaf(s, w0.w, acc[3]);
        acc[4]  = fmaf(s, w1.x, acc[4]);  acc[5]  = fmaf(s, w1.y, acc[5]);
        acc[6]  = fmaf(s, w1.z, acc[6]);  acc[7]  = fmaf(s, w1.w, acc[7]);
        acc[8]  = fmaf(s, w2.x, acc[8]);  acc[9]  = fmaf(s, w2.y, acc[9]);
        acc[10] = fmaf(s, w2.z, acc[10]); acc[11] = fmaf(s, w2.w, acc[11]);
        acc[12] = fmaf(s, w3.x, acc[12]); acc[13] = fmaf(s, w3.y, acc[13]);
        acc[14] = fmaf(s, w3.z, acc[14]); acc[15] = fmaf(s, w3.w, acc[15]);
    }
    // bf16 store: 16 cols = 32B (aligned: n*128 + q*32)
    unsigned int pk[8];
    #pragma unroll
    for (int p = 0; p < 8; p++)
        pk[p] = f2bf(acc[2 * p]) | (f2bf(acc[2 * p + 1]) << 16);
    uint4* ho = (uint4*)(h1b + (size_t)n * 64 + q * 16);
    ho[0] = make_uint4(pk[0], pk[1], pk[2], pk[3]);
    ho[1] = make_uint4(pk[4], pk[5], pk[6], pk[7]);
    // attention dots for heads 2q, 2q+1 (fp32 accumulators)
    #pragma unroll
    for (int hh = 0; hh < 2; hh++) {
        int head = q * 2 + hh;
        float s = 0.f, d = 0.f;
        #pragma unroll
        for (int ch = 0; ch < 8; ch++) {
            s = fmaf(acc[hh * 8 + ch], asrc[head * 8 + ch], s);
            d = fmaf(acc[hh * 8 + ch], adst[head * 8 + ch], d);
        }
        as1[n * 8 + head] = s;
        ad1[n * 8 + head] = d;
    }
}

// Per-dst softmax-weighted aggregation over in-edges (+ implicit self loop).
// Edge loop unrolled x8; h1 rows are bf16 (128B/row gather).
__global__ __launch_bounds__(256) void k_agg1(const ushort_t* __restrict__ h1b,
                                              const float* __restrict__ as1,
                                              const float* __restrict__ ad1,
                                              const float* __restrict__ b1,
                                              const int* __restrict__ rowptr,
                                              const int* __restrict__ csr,
                                              float* __restrict__ h2, int N) {
    int tid = threadIdx.x, lane = tid & 63;
    int n = blockIdx.x * 4 + (tid >> 6);
    if (n >= N) return;
    int myh = lane >> 3;
    float ad_d = ad1[n * 8 + myh];
    float e0 = as1[n * 8 + myh] + ad_d;  // self loop
    float w0s = __expf(e0 >= 0.f ? e0 : 0.2f * e0);
    float acc0 = w0s * bf2f(h1b[(size_t)n * 64 + lane]), z0 = w0s;
    float acc1 = 0.f, z1 = 0.f, acc2 = 0.f, z2 = 0.f, acc3 = 0.f, z3 = 0.f;
    int j0 = rowptr[n], j1 = rowptr[n + 1];
    int j = j0;
    for (; j + 8 <= j1; j += 8) {
        int s0 = csr[j + 0], s1 = csr[j + 1], s2 = csr[j + 2], s3 = csr[j + 3];
        int s4 = csr[j + 4], s5 = csr[j + 5], s6 = csr[j + 6], s7 = csr[j + 7];
        ushort_t u0 = h1b[(size_t)s0 * 64 + lane];
        ushort_t u1 = h1b[(size_t)s1 * 64 + lane];
        ushort_t u2 = h1b[(size_t)s2 * 64 + lane];
        ushort_t u3 = h1b[(size_t)s3 * 64 + lane];
        ushort_t u4 = h1b[(size_t)s4 * 64 + lane];
        ushort_t u5 = h1b[(size_t)s5 * 64 + lane];
        ushort_t u6 = h1b[(size_t)s6 * 64 + lane];
        ushort_t u7 = h1b[(size_t)s7 * 64 + lane];
        float a0 = as1[s0 * 8 + myh], a1 = as1[s1 * 8 + myh];
        float a2 = as1[s2 * 8 + myh], a3 = as1[s3 * 8 + myh];
        float a4 = as1[s4 * 8 + myh], a5 = as1[s5 * 8 + myh];
        float a6 = as1[s6 * 8 + myh], a7 = as1[s7 * 8 + myh];
        float q0 = a0 + ad_d, q1 = a1 + ad_d, q2 = a2 + ad_d, q3 = a3 + ad_d;
        float q4 = a4 + ad_d, q5 = a5 + ad_d, q6 = a6 + ad_d, q7 = a7 + ad_d;
        float w0 = __expf(q0 >= 0.f ? q0 : 0.2f * q0);
        float w1 = __expf(q1 >= 0.f ? q1 : 0.2f * q1);
        float w2 = __expf(q2 >= 0.f ? q2 : 0.2f * q2);
        float w3 = __expf(q3 >= 0.f ? q3 : 0.2f * q3);
        float w4 = __expf(q4 >= 0.f ? q4 : 0.2f * q4);
        float w5 = __expf(q5 >= 0.f ? q5 : 0.2f * q5);
        float w6 = __expf(q6 >= 0.f ? q6 : 0.2f * q6);
        float w7 = __expf(q7 >= 0.f ? q7 : 0.2f * q7);
        acc0 = fmaf(w0, bf2f(u0), acc0); z0 += w0;
        acc1 = fmaf(w1, bf2f(u1), acc1); z1 += w1;
        acc2 = fmaf(w2, bf2f(u2), acc2); z2 += w2;
        acc3 = fmaf(w3, bf2f(u3), acc3); z3 += w3;
        acc0 = fmaf(w4, bf2f(u4), acc0); z0 += w4;
        acc1 = fmaf(w5, bf2f(u5), acc1); z1 += w5;
        acc2 = fmaf(w6, bf2f(u6), acc2); z2 += w6;
        acc3 = fmaf(w7, bf2f(u7), acc3); z3 += w7;
    }
    for (; j < j1; ++j) {
        int s = csr[j];
        float e = as1[s * 8 + myh] + ad_d;
        float ww = __expf(e >= 0.f ? e : 0.2f * e);
        acc0 = fmaf(ww, bf2f(h1b[(size_t)s * 64 + lane]), acc0);
        z0 += ww;
    }
    float acc = (acc0 + acc1) + (acc2 + acc3);
    float z = (z0 + z1) + (z2 + z3);
    float v = acc / (z + 1e-16f) + b1[lane];
    h2[(size_t)n * 64 + lane] = v > 0.f ? v : (__expf(v) - 1.f);  // ELU
}

// gb[n][40](bf16) = h2[n] @ W2 ; as2/ad2 from fp32 accumulators.
// 2 threads per node; thread q owns columns [20q,20q+20).
__global__ __launch_bounds__(256) void k_xform2(const float* __restrict__ h2,
                                                const float* __restrict__ W2,
                                                const float* __restrict__ asrc2,
                                                const float* __restrict__ adst2,
                                                ushort_t* __restrict__ gb,
                                                float* __restrict__ as2,
                                                float* __restrict__ ad2, int N) {
    int t = blockIdx.x * 256 + threadIdx.x;
    int n = t >> 1, q = t & 1;
    if (n >= N) n = N - 1;
    const float4* hr = (const float4*)(h2 + (size_t)n * 64);
    float acc[20];
    #pragma unroll
    for (int c = 0; c < 20; c++) acc[c] = 0.f;
    float4 xv = hr[0];
    #pragma unroll 1
    for (int k4 = 0; k4 < 16; k4++) {
        float4 cur = xv;
        if (k4 < 15) xv = hr[k4 + 1];
        float xs[4] = {cur.x, cur.y, cur.z, cur.w};
        #pragma unroll
        for (int r = 0; r < 4; r++) {
            const float4* Wr = (const float4*)(W2 + (size_t)(k4 * 4 + r) * 40 + q * 20);
            float4 w0 = Wr[0], w1 = Wr[1], w2 = Wr[2], w3 = Wr[3], w4 = Wr[4];
            float s = xs[r];
            acc[0]  = fmaf(s, w0.x, acc[0]);  acc[1]  = fmaf(s, w0.y, acc[1]);
            acc[2]  = fmaf(s, w0.z, acc[2]);  acc[3]  = fmaf(s, w0.w, acc[3]);
            acc[4]  = fmaf(s, w1.x, acc[4]);  acc[5]  = fmaf(s, w1.y, acc[5]);
            acc[6]  = fmaf(s, w1.z, acc[6]);  acc[7]  = fmaf(s, w1.w, acc[7]);
            acc[8]  = fmaf(s, w2.x, acc[8]);  acc[9]  = fmaf(s, w2.y, acc[9]);
            acc[10] = fmaf(s, w2.z, acc[10]); acc[11] = fmaf(s, w2.w, acc[11]);
            acc[12] = fmaf(s, w3.x, acc[12]); acc[13] = fmaf(s, w3.y, acc[13]);
            acc[14] = fmaf(s, w3.z, acc[14]); acc[15] = fmaf(s, w3.w, acc[15]);
            acc[16] = fmaf(s, w4.x, acc[16]); acc[17] = fmaf(s, w4.y, acc[17]);
            acc[18] = fmaf(s, w4.z, acc[18]); acc[19] = fmaf(s, w4.w, acc[19]);
        }
    }
    // attention dots (partial over this thread's 20 cols, combine with sibling)
    float s = 0.f, d = 0.f;
    #pragma unroll
    for (int c = 0; c < 20; c++) {
        s = fmaf(acc[c], asrc2[q * 20 + c], s);
        d = fmaf(acc[c], adst2[q * 20 + c], d);
    }
    s += __shfl_xor(s, 1);
    d += __shfl_xor(d, 1);
    if (q == 0) { as2[n] = s; ad2[n] = d; }
    // bf16 store: 20 cols = 40B via 5 uint2 (8B-aligned: n*80 + q*40)
    unsigned int pk[10];
    #pragma unroll
    for (int p = 0; p < 10; p++)
        pk[p] = f2bf(acc[2 * p]) | (f2bf(acc[2 * p + 1]) << 16);
    uint2* go = (uint2*)(gb + (size_t)n * 40 + q * 20);
    #pragma unroll
    for (int p = 0; p < 5; p++)
        go[p] = make_uint2(pk[2 * p], pk[2 * p + 1]);
}

// Layer-2 aggregation + bias + log_softmax. Edge loop unrolled x8; g bf16.
__global__ __launch_bounds__(256) void k_agg2(const ushort_t* __restrict__ gb,
                                              const float* __restrict__ as2,
                                              const float* __restrict__ ad2,
                                              const float* __restrict__ b2,
                                              const int* __restrict__ rowptr,
                                              const int* __restrict__ csr,
                                              float* __restrict__ out, int N) {
    int tid = threadIdx.x, lane = tid & 63;
    int n = blockIdx.x * 4 + (tid >> 6);
    if (n >= N) return;
    int c = (lane < 40) ? lane : 0;
    float add = ad2[n];
    float e0 = as2[n] + add;
    float w0s = __expf(e0 >= 0.f ? e0 : 0.2f * e0);
    float acc0 = w0s * bf2f(gb[(size_t)n * 40 + c]), z0 = w0s;
    float acc1 = 0.f, z1 = 0.f, acc2 = 0.f, z2 = 0.f, acc3 = 0.f, z3 = 0.f;
    int j0 = rowptr[n], j1 = rowptr[n + 1];
    int j = j0;
    for (; j + 8 <= j1; j += 8) {
        int s0 = csr[j + 0], s1 = csr[j + 1], s2 = csr[j + 2], s3 = csr[j + 3];
        int s4 = csr[j + 4], s5 = csr[j + 5], s6 = csr[j + 6], s7 = csr[j + 7];
        ushort_t u0 = gb[(size_t)s0 * 40 + c];
        ushort_t u1 = gb[(size_t)s1 * 40 + c];
        ushort_t u2 = gb[(size_t)s2 * 40 + c];
        ushort_t u3 = gb[(size_t)s3 * 40 + c];
        ushort_t u4 = gb[(size_t)s4 * 40 + c];
        ushort_t u5 = gb[(size_t)s5 * 40 + c];
        ushort_t u6 = gb[(size_t)s6 * 40 + c];
        ushort_t u7 = gb[(size_t)s7 * 40 + c];
        float a0 = as2[s0], a1 = as2[s1], a2 = as2[s2], a3 = as2[s3];
        float a4 = as2[s4], a5 = as2[s5], a6 = as2[s6], a7 = as2[s7];
        float q0 = a0 + add, q1 = a1 + add, q2 = a2 + add, q3 = a3 + add;
        float q4 = a4 + add, q5 = a5 + add, q6 = a6 + add, q7 = a7 + add;
        float w0 = __expf(q0 >= 0.f ? q0 : 0.2f * q0);
        float w1 = __expf(q1 >= 0.f ? q1 : 0.2f * q1);
        float w2 = __expf(q2 >= 0.f ? q2 : 0.2f * q2);
        float w3 = __expf(q3 >= 0.f ? q3 : 0.2f * q3);
        float w4 = __expf(q4 >= 0.f ? q4 : 0.2f * q4);
        float w5 = __expf(q5 >= 0.f ? q5 : 0.2f * q5);
        float w6 = __expf(q6 >= 0.f ? q6 : 0.2f * q6);
        float w7 = __expf(q7 >= 0.f ? q7 : 0.2f * q7);
        acc0 = fmaf(w0, bf2f(u0), acc0); z0 += w0;
        acc1 = fmaf(w1, bf2f(u1), acc1); z1 += w1;
        acc2 = fmaf(w2, bf2f(u2), acc2); z2 += w2;
        acc3 = fmaf(w3, bf2f(u3), acc3); z3 += w3;
        acc0 = fmaf(w4, bf2f(u4), acc0); z0 += w4;
        acc1 = fmaf(w5, bf2f(u5), acc1); z1 += w5;
        acc2 = fmaf(w6, bf2f(u6), acc2); z2 += w6;
        acc3 = fmaf(w7, bf2f(u7), acc3); z3 += w7;
    }
    for (; j < j1; ++j) {
        int s = csr[j];
        float e = as2[s] + add;
        float ww = __expf(e >= 0.f ? e : 0.2f * e);
        acc0 = fmaf(ww, bf2f(gb[(size_t)s * 40 + c]), acc0);
        z0 += ww;
    }
    float acc = (acc0 + acc1) + (acc2 + acc3);
    float z = (z0 + z1) + (z2 + z3);
    float logit = acc / (z + 1e-16f) + b2[c];
    float mv = (lane < 40) ? logit : -INFINITY;
    #pragma unroll
    for (int ofs = 1; ofs < 64; ofs <<= 1) mv = fmaxf(mv, __shfl_xor(mv, ofs));
    float ev = (lane < 40) ? __expf(logit - mv) : 0.f;
    #pragma unroll
    for (int ofs = 1; ofs < 64; ofs <<= 1) ev += __shfl_xor(ev, ofs);
    if (lane < 40) out[n * 40 + lane] = logit - mv - __logf(ev);
}

extern "C" void kernel_launch(void* const* d_in, const int* in_sizes, int n_in,
                              void* d_out, int out_size, void* d_ws, size_t ws_size,
                              hipStream_t stream) {
    const float* x    = (const float*)d_in[0];
    const float* topo = (const float*)d_in[1];
    const int*   ei   = (const int*)d_in[2];
    const float* W1   = (const float*)d_in[3];
    const float* a_s1 = (const float*)d_in[4];
    const float* a_d1 = (const float*)d_in[5];
    const float* b1   = (const float*)d_in[6];
    const float* W2   = (const float*)d_in[7];
    const float* a_s2 = (const float*)d_in[8];
    const float* a_d2 = (const float*)d_in[9];
    const float* b2   = (const float*)d_in[10];
    float* out = (float*)d_out;

    int N = in_sizes[0] / 128;
    int E = in_sizes[2] / 2;
    const int* esrc = ei;
    const int* edst = ei + E;
    int NBUK = (N + 255) / 256;

    char* ws = (char*)d_ws;
    size_t off = 0;
    auto alloc = [&](size_t bytes) -> void* {
        void* p = ws + off;
        off = (off + bytes + 255) & ~(size_t)255;
        return p;
    };
    ushort_t* h1b  = (ushort_t*)alloc((size_t)N * 64 * 2);
    float* as1     = (float*)alloc((size_t)N * 8 * 4);
    float* ad1     = (float*)alloc((size_t)N * 8 * 4);
    float* h2      = (float*)alloc((size_t)N * 64 * 4);
    ushort_t* gb   = (ushort_t*)alloc((size_t)N * 40 * 2);
    float* as2     = (float*)alloc((size_t)N * 4);
    float* ad2     = (float*)alloc((size_t)N * 4);
    int*   rowptr  = (int*)alloc((size_t)(N + 1) * 4);
    int*   csr     = (int*)alloc((size_t)E * 4);
    unsigned int* tmp = (unsigned int*)alloc((size_t)E * 4);
    int* bucketCnt = (int*)alloc((size_t)(NBUK + 1) * 4);
    int* bucketOff = (int*)alloc((size_t)(NBUK + 1) * 4);
    int* gCursor   = (int*)alloc((size_t)NBUK * 4);

    hipMemsetAsync(bucketCnt, 0, (size_t)(NBUK + 1) * 4, stream);
    k_bhist<<<256, 256, 0, stream>>>(edst, bucketCnt, E, NBUK);
    k_bscan<<<1, 64, 0, stream>>>(bucketCnt, bucketOff, gCursor, rowptr, N, E, NBUK);
    int nbin = (E + BIN_CHUNK - 1) / BIN_CHUNK;
    k_bin<<<nbin, 256, 0, stream>>>(esrc, edst, gCursor, tmp, E, NBUK);
    k_fill2<<<NBUK, 256, 0, stream>>>(tmp, bucketOff, rowptr, csr, N);

    int nbx1 = ((N * 4) + 255) / 256;  // 4 threads per node
    int nbx2 = ((N * 2) + 255) / 256;  // 2 threads per node
    int nb4  = (N + 3) / 4;            // 1 node/wave x 4 waves/block
    k_xform1<<<nbx1, 256, 0, stream>>>(x, topo, W1, a_s1, a_d1, h1b, as1, ad1, N);
    k_agg1<<<nb4, 256, 0, stream>>>(h1b, as1, ad1, b1, rowptr, csr, h2, N);
    k_xform2<<<nbx2, 256, 0, stream>>>(h2, W2, a_s2, a_d2, gb, as2, ad2, N);
    k_agg2<<<nb4, 256, 0, stream>>>(gb, as2, ad2, b2, rowptr, csr, out, N);
}

// Round 8
// 405.916 us; speedup vs baseline: 1.4682x; 1.4682x over previous
//
#include <hip/hip_runtime.h>
#include <math.h>

// ---------------------------------------------------------------------------
// TopoGAT: 2-layer GAT on MI355X.
// R2: agg kernels unrolled x8 (8 outstanding row gathers/wave).
// R3: CSR build via two-level binning (write-locality; ~1x writeback).
// R5: gather tables h1/g stored in bf16 (halves random-gather fabric bytes).
// R7: xform kernels as 2D register-tiled GEMM: W staged ONCE per block in LDS
//     (R6 had every wave re-streaming 35KB W from L2 -> request storm, 13%
//     VALUBusy), x staged transposed in LDS. Thread tile 4x4, per k:
//     2x ds_read_b128 (24cy) vs 16 FMA (32cy) -> VALU-bound by construction.
// ---------------------------------------------------------------------------

#define NBUK_MAX 512
#define BIN_CHUNK 4096

typedef unsigned short ushort_t;

__device__ inline unsigned int f2bf(float f) {  // RNE fp32->bf16
    unsigned int u = __float_as_uint(f);
    u += 0x7FFFu + ((u >> 16) & 1u);
    return u >> 16;
}
__device__ inline float bf2f(ushort_t b) {
    return __uint_as_float((unsigned int)b << 16);
}

__device__ inline int wave_incl_scan(int v, int lane) {
    #pragma unroll
    for (int ofs = 1; ofs < 64; ofs <<= 1) {
        int t = __shfl_up(v, ofs);
        if (lane >= ofs) v += t;
    }
    return v;
}

// Bucket histogram (bucket = dst>>8), LDS-aggregated.
__global__ __launch_bounds__(256) void k_bhist(const int* __restrict__ dst,
                                               int* __restrict__ bucketCnt,
                                               int E, int NBUK) {
    __shared__ int h[NBUK_MAX];
    int tid = threadIdx.x;
    for (int i = tid; i < NBUK; i += 256) h[i] = 0;
    __syncthreads();
    for (int i = blockIdx.x * 256 + tid; i < E; i += gridDim.x * 256)
        atomicAdd(&h[dst[i] >> 8], 1);
    __syncthreads();
    for (int i = tid; i < NBUK; i += 256) {
        int c = h[i];
        if (c) atomicAdd(&bucketCnt[i], c);
    }
}

// One-wave exclusive scan of bucket counts -> bucketOff, gCursor.
__global__ void k_bscan(const int* __restrict__ bucketCnt,
                        int* __restrict__ bucketOff, int* __restrict__ gCursor,
                        int* __restrict__ rowptr, int N, int E, int NBUK) {
    int lane = threadIdx.x & 63;
    int running = 0;
    for (int base = 0; base < NBUK; base += 64) {
        int idx = base + lane;
        int v = (idx < NBUK) ? bucketCnt[idx] : 0;
        int incl = wave_incl_scan(v, lane);
        int excl = running + incl - v;
        if (idx < NBUK) { bucketOff[idx] = excl; gCursor[idx] = excl; }
        running += __shfl(incl, 63);
    }
    if (lane == 0) { bucketOff[NBUK] = running; rowptr[N] = E; }
}

// Bin edges into bucket-contiguous tmp. One global atomic per (block,bucket);
// packed word = (src<<8) | (dst&255).
__global__ __launch_bounds__(256) void k_bin(const int* __restrict__ src,
                                             const int* __restrict__ dst,
                                             int* __restrict__ gCursor,
                                             unsigned int* __restrict__ tmp,
                                             int E, int NBUK) {
    __shared__ int lcnt[NBUK_MAX];
    __shared__ int lcur[NBUK_MAX];
    int tid = threadIdx.x;
    int base = blockIdx.x * BIN_CHUNK;
    for (int i = tid; i < NBUK; i += 256) lcnt[i] = 0;
    __syncthreads();
    #pragma unroll
    for (int k = 0; k < BIN_CHUNK / 256; k++) {
        int i = base + tid + k * 256;
        if (i < E) atomicAdd(&lcnt[dst[i] >> 8], 1);
    }
    __syncthreads();
    for (int b = tid; b < NBUK; b += 256) {
        int c = lcnt[b];
        lcur[b] = c ? atomicAdd(&gCursor[b], c) : 0;
    }
    __syncthreads();
    #pragma unroll
    for (int k = 0; k < BIN_CHUNK / 256; k++) {
        int i = base + tid + k * 256;
        if (i < E) {
            int d = dst[i];
            int p = atomicAdd(&lcur[d >> 8], 1);
            tmp[p] = ((unsigned int)src[i] << 8) | (unsigned int)(d & 255);
        }
    }
}

// Exact CSR fill within a bucket; csr writes confined to block-owned window.
__global__ __launch_bounds__(256) void k_fill2(const unsigned int* __restrict__ tmp,
                                               const int* __restrict__ bucketOff,
                                               int* __restrict__ rowptr,
                                               int* __restrict__ csr, int N) {
    __shared__ int cnt[256];
    __shared__ int cur[256];
    __shared__ int wsum[4];
    int b = blockIdx.x, tid = threadIdx.x;
    int lane = tid & 63, wv = tid >> 6;
    int e0 = bucketOff[b], e1 = bucketOff[b + 1];
    cnt[tid] = 0;
    __syncthreads();
    for (int i = e0 + tid; i < e1; i += 256)
        atomicAdd(&cnt[tmp[i] & 255u], 1);
    __syncthreads();
    int v = cnt[tid];
    int incl = wave_incl_scan(v, lane);
    if (lane == 63) wsum[wv] = incl;
    __syncthreads();
    int woff = 0;
    for (int i = 0; i < wv; i++) woff += wsum[i];
    int excl = woff + incl - v;
    int node = b * 256 + tid;
    if (node < N) rowptr[node] = e0 + excl;
    cur[tid] = e0 + excl;
    __syncthreads();
    for (int i = e0 + tid; i < e1; i += 256) {
        unsigned int t = tmp[i];
        int p = atomicAdd(&cur[t & 255u], 1);
        csr[p] = (int)(t >> 8);
    }
}

// h1b[n][64](bf16) = [x[n]|topo[n]] @ W1 ; as1/ad1 from fp32 accumulators.
// Block = 64 nodes x 64 cols GEMM tile, K=136. W1 + xT staged in LDS.
// Thread = 4 nodes x 4 cols (acc[16]); per k: 2 ds_read_b128 + 16 FMA.
__global__ __launch_bounds__(256) void k_xform1(const float* __restrict__ x,
                                                const float* __restrict__ topo,
                                                const float* __restrict__ W1,
                                                const float* __restrict__ asrc,
                                                const float* __restrict__ adst,
                                                ushort_t* __restrict__ h1b,
                                                float* __restrict__ as1,
                                                float* __restrict__ ad1, int N) {
    __shared__ float XT[136 * 64];  // XT[k][node]
    __shared__ float WS[136 * 64];  // WS[k][col]
    int tid = threadIdx.x;
    int n0 = blockIdx.x * 64;
    {   // stage W1: 8704 floats = 2176 float4 (once per block)
        const float4* W4 = (const float4*)W1;
        float4* WS4 = (float4*)WS;
        for (int i = tid; i < 2176; i += 256) WS4[i] = W4[i];
    }
    {   // stage x transposed: 64 nodes x 32 float4
        const float4* x4 = (const float4*)x;
        for (int i = tid; i < 2048; i += 256) {
            int node = i >> 5, k4 = i & 31;
            int gn = n0 + node; if (gn > N - 1) gn = N - 1;
            float4 v = x4[(size_t)gn * 32 + k4];
            int k = k4 * 4;
            XT[(k + 0) * 64 + node] = v.x;
            XT[(k + 1) * 64 + node] = v.y;
            XT[(k + 2) * 64 + node] = v.z;
            XT[(k + 3) * 64 + node] = v.w;
        }
        // topo rows 128..135: 64 nodes x 2 float4
        const float4* t4 = (const float4*)topo;
        if (tid < 128) {
            int node = tid >> 1, k4 = tid & 1;
            int gn = n0 + node; if (gn > N - 1) gn = N - 1;
            float4 v = t4[(size_t)gn * 2 + k4];
            int k = 128 + k4 * 4;
            XT[(k + 0) * 64 + node] = v.x;
            XT[(k + 1) * 64 + node] = v.y;
            XT[(k + 2) * 64 + node] = v.z;
            XT[(k + 3) * 64 + node] = v.w;
        }
    }
    __syncthreads();
    int ci = tid & 15, ni = tid >> 4;
    int nb = ni * 4, cb = ci * 4;
    float acc[16];
    #pragma unroll
    for (int i = 0; i < 16; i++) acc[i] = 0.f;
    #pragma unroll 4
    for (int k = 0; k < 136; k++) {
        float4 xv = *(const float4*)&XT[k * 64 + nb];
        float4 wv = *(const float4*)&WS[k * 64 + cb];
        acc[0]  = fmaf(xv.x, wv.x, acc[0]);  acc[1]  = fmaf(xv.x, wv.y, acc[1]);
        acc[2]  = fmaf(xv.x, wv.z, acc[2]);  acc[3]  = fmaf(xv.x, wv.w, acc[3]);
        acc[4]  = fmaf(xv.y, wv.x, acc[4]);  acc[5]  = fmaf(xv.y, wv.y, acc[5]);
        acc[6]  = fmaf(xv.y, wv.z, acc[6]);  acc[7]  = fmaf(xv.y, wv.w, acc[7]);
        acc[8]  = fmaf(xv.z, wv.x, acc[8]);  acc[9]  = fmaf(xv.z, wv.y, acc[9]);
        acc[10] = fmaf(xv.z, wv.z, acc[10]); acc[11] = fmaf(xv.z, wv.w, acc[11]);
        acc[12] = fmaf(xv.w, wv.x, acc[12]); acc[13] = fmaf(xv.w, wv.y, acc[13]);
        acc[14] = fmaf(xv.w, wv.z, acc[14]); acc[15] = fmaf(xv.w, wv.w, acc[15]);
    }
    int head = cb >> 3;  // cols cb..cb+3 lie in one head (cb multiple of 4)
    #pragma unroll
    for (int i = 0; i < 4; i++) {
        int n = n0 + nb + i;
        unsigned int p0 = f2bf(acc[i * 4 + 0]) | (f2bf(acc[i * 4 + 1]) << 16);
        unsigned int p1 = f2bf(acc[i * 4 + 2]) | (f2bf(acc[i * 4 + 3]) << 16);
        if (n < N) *(uint2*)&h1b[(size_t)n * 64 + cb] = make_uint2(p0, p1);
        float s = 0.f, d = 0.f;
        #pragma unroll
        for (int j = 0; j < 4; j++) {
            s = fmaf(acc[i * 4 + j], asrc[cb + j], s);
            d = fmaf(acc[i * 4 + j], adst[cb + j], d);
        }
        s += __shfl_xor(s, 1);  // combine the two half-head threads
        d += __shfl_xor(d, 1);
        if ((ci & 1) == 0 && n < N) {
            as1[n * 8 + head] = s;
            ad1[n * 8 + head] = d;
        }
    }
}

// Per-dst softmax-weighted aggregation over in-edges (+ implicit self loop).
// Edge loop unrolled x8; h1 rows are bf16 (128B/row gather).
__global__ __launch_bounds__(256) void k_agg1(const ushort_t* __restrict__ h1b,
                                              const float* __restrict__ as1,
                                              const float* __restrict__ ad1,
                                              const float* __restrict__ b1,
                                              const int* __restrict__ rowptr,
                                              const int* __restrict__ csr,
                                              float* __restrict__ h2, int N) {
    int tid = threadIdx.x, lane = tid & 63;
    int n = blockIdx.x * 4 + (tid >> 6);
    if (n >= N) return;
    int myh = lane >> 3;
    float ad_d = ad1[n * 8 + myh];
    float e0 = as1[n * 8 + myh] + ad_d;  // self loop
    float w0s = __expf(e0 >= 0.f ? e0 : 0.2f * e0);
    float acc0 = w0s * bf2f(h1b[(size_t)n * 64 + lane]), z0 = w0s;
    float acc1 = 0.f, z1 = 0.f, acc2 = 0.f, z2 = 0.f, acc3 = 0.f, z3 = 0.f;
    int j0 = rowptr[n], j1 = rowptr[n + 1];
    int j = j0;
    for (; j + 8 <= j1; j += 8) {
        int s0 = csr[j + 0], s1 = csr[j + 1], s2 = csr[j + 2], s3 = csr[j + 3];
        int s4 = csr[j + 4], s5 = csr[j + 5], s6 = csr[j + 6], s7 = csr[j + 7];
        ushort_t u0 = h1b[(size_t)s0 * 64 + lane];
        ushort_t u1 = h1b[(size_t)s1 * 64 + lane];
        ushort_t u2 = h1b[(size_t)s2 * 64 + lane];
        ushort_t u3 = h1b[(size_t)s3 * 64 + lane];
        ushort_t u4 = h1b[(size_t)s4 * 64 + lane];
        ushort_t u5 = h1b[(size_t)s5 * 64 + lane];
        ushort_t u6 = h1b[(size_t)s6 * 64 + lane];
        ushort_t u7 = h1b[(size_t)s7 * 64 + lane];
        float a0 = as1[s0 * 8 + myh], a1 = as1[s1 * 8 + myh];
        float a2 = as1[s2 * 8 + myh], a3 = as1[s3 * 8 + myh];
        float a4 = as1[s4 * 8 + myh], a5 = as1[s5 * 8 + myh];
        float a6 = as1[s6 * 8 + myh], a7 = as1[s7 * 8 + myh];
        float q0 = a0 + ad_d, q1 = a1 + ad_d, q2 = a2 + ad_d, q3 = a3 + ad_d;
        float q4 = a4 + ad_d, q5 = a5 + ad_d, q6 = a6 + ad_d, q7 = a7 + ad_d;
        float w0 = __expf(q0 >= 0.f ? q0 : 0.2f * q0);
        float w1 = __expf(q1 >= 0.f ? q1 : 0.2f * q1);
        float w2 = __expf(q2 >= 0.f ? q2 : 0.2f * q2);
        float w3 = __expf(q3 >= 0.f ? q3 : 0.2f * q3);
        float w4 = __expf(q4 >= 0.f ? q4 : 0.2f * q4);
        float w5 = __expf(q5 >= 0.f ? q5 : 0.2f * q5);
        float w6 = __expf(q6 >= 0.f ? q6 : 0.2f * q6);
        float w7 = __expf(q7 >= 0.f ? q7 : 0.2f * q7);
        acc0 = fmaf(w0, bf2f(u0), acc0); z0 += w0;
        acc1 = fmaf(w1, bf2f(u1), acc1); z1 += w1;
        acc2 = fmaf(w2, bf2f(u2), acc2); z2 += w2;
        acc3 = fmaf(w3, bf2f(u3), acc3); z3 += w3;
        acc0 = fmaf(w4, bf2f(u4), acc0); z0 += w4;
        acc1 = fmaf(w5, bf2f(u5), acc1); z1 += w5;
        acc2 = fmaf(w6, bf2f(u6), acc2); z2 += w6;
        acc3 = fmaf(w7, bf2f(u7), acc3); z3 += w7;
    }
    for (; j < j1; ++j) {
        int s = csr[j];
        float e = as1[s * 8 + myh] + ad_d;
        float ww = __expf(e >= 0.f ? e : 0.2f * e);
        acc0 = fmaf(ww, bf2f(h1b[(size_t)s * 64 + lane]), acc0);
        z0 += ww;
    }
    float acc = (acc0 + acc1) + (acc2 + acc3);
    float z = (z0 + z1) + (z2 + z3);
    float v = acc / (z + 1e-16f) + b1[lane];
    h2[(size_t)n * 64 + lane] = v > 0.f ? v : (__expf(v) - 1.f);  // ELU
}

// gb[n][40](bf16) = h2[n] @ W2 ; as2/ad2 from fp32 accumulators.
// Block = 64 nodes x 40 cols GEMM tile, K=64. Same LDS structure as k_xform1.
__global__ __launch_bounds__(256) void k_xform2(const float* __restrict__ h2,
                                                const float* __restrict__ W2,
                                                const float* __restrict__ asrc2,
                                                const float* __restrict__ adst2,
                                                ushort_t* __restrict__ gb,
                                                float* __restrict__ as2,
                                                float* __restrict__ ad2, int N) {
    __shared__ float XT[64 * 64];  // h2T[k][node]
    __shared__ float WS[64 * 40];  // WS[k][col]
    int tid = threadIdx.x;
    int n0 = blockIdx.x * 64;
    {   // stage W2: 2560 floats = 640 float4
        const float4* W4 = (const float4*)W2;
        float4* WS4 = (float4*)WS;
        for (int i = tid; i < 640; i += 256) WS4[i] = W4[i];
    }
    {   // stage h2 transposed: 64 nodes x 16 float4
        const float4* h4 = (const float4*)h2;
        for (int i = tid; i < 1024; i += 256) {
            int node = i >> 4, k4 = i & 15;
            int gn = n0 + node; if (gn > N - 1) gn = N - 1;
            float4 v = h4[(size_t)gn * 16 + k4];
            int k = k4 * 4;
            XT[(k + 0) * 64 + node] = v.x;
            XT[(k + 1) * 64 + node] = v.y;
            XT[(k + 2) * 64 + node] = v.z;
            XT[(k + 3) * 64 + node] = v.w;
        }
    }
    __syncthreads();
    int ci = tid & 15, ni = tid >> 4;
    int nb = ni * 4, cb = ci * 4;
    float acc[16];
    #pragma unroll
    for (int i = 0; i < 16; i++) acc[i] = 0.f;
    if (ci < 10) {
        #pragma unroll 4
        for (int k = 0; k < 64; k++) {
            float4 xv = *(const float4*)&XT[k * 64 + nb];
            float4 wv = *(const float4*)&WS[k * 40 + cb];
            acc[0]  = fmaf(xv.x, wv.x, acc[0]);  acc[1]  = fmaf(xv.x, wv.y, acc[1]);
            acc[2]  = fmaf(xv.x, wv.z, acc[2]);  acc[3]  = fmaf(xv.x, wv.w, acc[3]);
            acc[4]  = fmaf(xv.y, wv.x, acc[4]);  acc[5]  = fmaf(xv.y, wv.y, acc[5]);
            acc[6]  = fmaf(xv.y, wv.z, acc[6]);  acc[7]  = fmaf(xv.y, wv.w, acc[7]);
            acc[8]  = fmaf(xv.z, wv.x, acc[8]);  acc[9]  = fmaf(xv.z, wv.y, acc[9]);
            acc[10] = fmaf(xv.z, wv.z, acc[10]); acc[11] = fmaf(xv.z, wv.w, acc[11]);
            acc[12] = fmaf(xv.w, wv.x, acc[12]); acc[13] = fmaf(xv.w, wv.y, acc[13]);
            acc[14] = fmaf(xv.w, wv.z, acc[14]); acc[15] = fmaf(xv.w, wv.w, acc[15]);
        }
    }
    #pragma unroll
    for (int i = 0; i < 4; i++) {
        int n = n0 + nb + i;
        if (ci < 10 && n < N) {
            unsigned int p0 = f2bf(acc[i * 4 + 0]) | (f2bf(acc[i * 4 + 1]) << 16);
            unsigned int p1 = f2bf(acc[i * 4 + 2]) | (f2bf(acc[i * 4 + 3]) << 16);
            *(uint2*)&gb[(size_t)n * 40 + cb] = make_uint2(p0, p1);
        }
        float s = 0.f, d = 0.f;
        if (ci < 10) {
            #pragma unroll
            for (int j = 0; j < 4; j++) {
                s = fmaf(acc[i * 4 + j], asrc2[cb + j], s);
                d = fmaf(acc[i * 4 + j], adst2[cb + j], d);
            }
        }
        // reduce over the 16-lane ci group (ci>=10 contribute 0)
        s += __shfl_xor(s, 1); s += __shfl_xor(s, 2);
        s += __shfl_xor(s, 4); s += __shfl_xor(s, 8);
        d += __shfl_xor(d, 1); d += __shfl_xor(d, 2);
        d += __shfl_xor(d, 4); d += __shfl_xor(d, 8);
        if (ci == 0 && n < N) { as2[n] = s; ad2[n] = d; }
    }
}

// Layer-2 aggregation + bias + log_softmax. Edge loop unrolled x8; g bf16.
__global__ __launch_bounds__(256) void k_agg2(const ushort_t* __restrict__ gb,
                                              const float* __restrict__ as2,
                                              const float* __restrict__ ad2,
                                              const float* __restrict__ b2,
                                              const int* __restrict__ rowptr,
                                              const int* __restrict__ csr,
                                              float* __restrict__ out, int N) {
    int tid = threadIdx.x, lane = tid & 63;
    int n = blockIdx.x * 4 + (tid >> 6);
    if (n >= N) return;
    int c = (lane < 40) ? lane : 0;
    float add = ad2[n];
    float e0 = as2[n] + add;
    float w0s = __expf(e0 >= 0.f ? e0 : 0.2f * e0);
    float acc0 = w0s * bf2f(gb[(size_t)n * 40 + c]), z0 = w0s;
    float acc1 = 0.f, z1 = 0.f, acc2 = 0.f, z2 = 0.f, acc3 = 0.f, z3 = 0.f;
    int j0 = rowptr[n], j1 = rowptr[n + 1];
    int j = j0;
    for (; j + 8 <= j1; j += 8) {
        int s0 = csr[j + 0], s1 = csr[j + 1], s2 = csr[j + 2], s3 = csr[j + 3];
        int s4 = csr[j + 4], s5 = csr[j + 5], s6 = csr[j + 6], s7 = csr[j + 7];
        ushort_t u0 = gb[(size_t)s0 * 40 + c];
        ushort_t u1 = gb[(size_t)s1 * 40 + c];
        ushort_t u2 = gb[(size_t)s2 * 40 + c];
        ushort_t u3 = gb[(size_t)s3 * 40 + c];
        ushort_t u4 = gb[(size_t)s4 * 40 + c];
        ushort_t u5 = gb[(size_t)s5 * 40 + c];
        ushort_t u6 = gb[(size_t)s6 * 40 + c];
        ushort_t u7 = gb[(size_t)s7 * 40 + c];
        float a0 = as2[s0], a1 = as2[s1], a2 = as2[s2], a3 = as2[s3];
        float a4 = as2[s4], a5 = as2[s5], a6 = as2[s6], a7 = as2[s7];
        float q0 = a0 + add, q1 = a1 + add, q2 = a2 + add, q3 = a3 + add;
        float q4 = a4 + add, q5 = a5 + add, q6 = a6 + add, q7 = a7 + add;
        float w0 = __expf(q0 >= 0.f ? q0 : 0.2f * q0);
        float w1 = __expf(q1 >= 0.f ? q1 : 0.2f * q1);
        float w2 = __expf(q2 >= 0.f ? q2 : 0.2f * q2);
        float w3 = __expf(q3 >= 0.f ? q3 : 0.2f * q3);
        float w4 = __expf(q4 >= 0.f ? q4 : 0.2f * q4);
        float w5 = __expf(q5 >= 0.f ? q5 : 0.2f * q5);
        float w6 = __expf(q6 >= 0.f ? q6 : 0.2f * q6);
        float w7 = __expf(q7 >= 0.f ? q7 : 0.2f * q7);
        acc0 = fmaf(w0, bf2f(u0), acc0); z0 += w0;
        acc1 = fmaf(w1, bf2f(u1), acc1); z1 += w1;
        acc2 = fmaf(w2, bf2f(u2), acc2); z2 += w2;
        acc3 = fmaf(w3, bf2f(u3), acc3); z3 += w3;
        acc0 = fmaf(w4, bf2f(u4), acc0); z0 += w4;
        acc1 = fmaf(w5, bf2f(u5), acc1); z1 += w5;
        acc2 = fmaf(w6, bf2f(u6), acc2); z2 += w6;
        acc3 = fmaf(w7, bf2f(u7), acc3); z3 += w7;
    }
    for (; j < j1; ++j) {
        int s = csr[j];
        float e = as2[s] + add;
        float ww = __expf(e >= 0.f ? e : 0.2f * e);
        acc0 = fmaf(ww, bf2f(gb[(size_t)s * 40 + c]), acc0);
        z0 += ww;
    }
    float acc = (acc0 + acc1) + (acc2 + acc3);
    float z = (z0 + z1) + (z2 + z3);
    float logit = acc / (z + 1e-16f) + b2[c];
    float mv = (lane < 40) ? logit : -INFINITY;
    #pragma unroll
    for (int ofs = 1; ofs < 64; ofs <<= 1) mv = fmaxf(mv, __shfl_xor(mv, ofs));
    float ev = (lane < 40) ? __expf(logit - mv) : 0.f;
    #pragma unroll
    for (int ofs = 1; ofs < 64; ofs <<= 1) ev += __shfl_xor(ev, ofs);
    if (lane < 40) out[n * 40 + lane] = logit - mv - __logf(ev);
}

extern "C" void kernel_launch(void* const* d_in, const int* in_sizes, int n_in,
                              void* d_out, int out_size, void* d_ws, size_t ws_size,
                              hipStream_t stream) {
    const float* x    = (const float*)d_in[0];
    const float* topo = (const float*)d_in[1];
    const int*   ei   = (const int*)d_in[2];
    const float* W1   = (const float*)d_in[3];
    const float* a_s1 = (const float*)d_in[4];
    const float* a_d1 = (const float*)d_in[5];
    const float* b1   = (const float*)d_in[6];
    const float* W2   = (const float*)d_in[7];
    const float* a_s2 = (const float*)d_in[8];
    const float* a_d2 = (const float*)d_in[9];
    const float* b2   = (const float*)d_in[10];
    float* out = (float*)d_out;

    int N = in_sizes[0] / 128;
    int E = in_sizes[2] / 2;
    const int* esrc = ei;
    const int* edst = ei + E;
    int NBUK = (N + 255) / 256;

    char* ws = (char*)d_ws;
    size_t off = 0;
    auto alloc = [&](size_t bytes) -> void* {
        void* p = ws + off;
        off = (off + bytes + 255) & ~(size_t)255;
        return p;
    };
    ushort_t* h1b  = (ushort_t*)alloc((size_t)N * 64 * 2);
    float* as1     = (float*)alloc((size_t)N * 8 * 4);
    float* ad1     = (float*)alloc((size_t)N * 8 * 4);
    float* h2      = (float*)alloc((size_t)N * 64 * 4);
    ushort_t* gb   = (ushort_t*)alloc((size_t)N * 40 * 2);
    float* as2     = (float*)alloc((size_t)N * 4);
    float* ad2     = (float*)alloc((size_t)N * 4);
    int*   rowptr  = (int*)alloc((size_t)(N + 1) * 4);
    int*   csr     = (int*)alloc((size_t)E * 4);
    unsigned int* tmp = (unsigned int*)alloc((size_t)E * 4);
    int* bucketCnt = (int*)alloc((size_t)(NBUK + 1) * 4);
    int* bucketOff = (int*)alloc((size_t)(NBUK + 1) * 4);
    int* gCursor   = (int*)alloc((size_t)NBUK * 4);

    hipMemsetAsync(bucketCnt, 0, (size_t)(NBUK + 1) * 4, stream);
    k_bhist<<<256, 256, 0, stream>>>(edst, bucketCnt, E, NBUK);
    k_bscan<<<1, 64, 0, stream>>>(bucketCnt, bucketOff, gCursor, rowptr, N, E, NBUK);
    int nbin = (E + BIN_CHUNK - 1) / BIN_CHUNK;
    k_bin<<<nbin, 256, 0, stream>>>(esrc, edst, gCursor, tmp, E, NBUK);
    k_fill2<<<NBUK, 256, 0, stream>>>(tmp, bucketOff, rowptr, csr, N);

    int nbg = (N + 63) / 64;  // 64-node GEMM tiles
    int nb4 = (N + 3) / 4;    // 1 node/wave x 4 waves/block
    k_xform1<<<nbg, 256, 0, stream>>>(x, topo, W1, a_s1, a_d1, h1b, as1, ad1, N);
    k_agg1<<<nb4, 256, 0, stream>>>(h1b, as1, ad1, b1, rowptr, csr, h2, N);
    k_xform2<<<nbg, 256, 0, stream>>>(h2, W2, a_s2, a_d2, gb, as2, ad2, N);
    k_agg2<<<nb4, 256, 0, stream>>>(gb, as2, ad2, b2, rowptr, csr, out, N);
}

// Round 9
// 387.776 us; speedup vs baseline: 1.5369x; 1.0468x over previous
//
#include <hip/hip_runtime.h>
#include <math.h>

// ---------------------------------------------------------------------------
// TopoGAT: 2-layer GAT on MI355X.
// R3: CSR build via two-level binning (write-locality; ~1x writeback).
// R5: gather tables h1/g stored in bf16 (halves random-gather fabric bytes).
// R7: xform kernels as 2D register-tiled GEMM (W+xT in LDS, 4x4 thread tile).
// R8: agg kernels were VALU-bound on redundant exp: every lane recomputed the
//     same per-edge attention weights (64x redundancy in agg2, 8x in agg1).
//     Now ONE wave-wide exp computes all 8 chunk weights (agg1: 8 edges x 8
//     heads = 64 lanes exactly); distributed via __shfl/bpermute (DS pipe,
//     idle here). Bytes and numerics unchanged.
// ---------------------------------------------------------------------------

#define NBUK_MAX 512
#define BIN_CHUNK 4096

typedef unsigned short ushort_t;

__device__ inline unsigned int f2bf(float f) {  // RNE fp32->bf16
    unsigned int u = __float_as_uint(f);
    u += 0x7FFFu + ((u >> 16) & 1u);
    return u >> 16;
}
__device__ inline float bf2f(ushort_t b) {
    return __uint_as_float((unsigned int)b << 16);
}

__device__ inline int wave_incl_scan(int v, int lane) {
    #pragma unroll
    for (int ofs = 1; ofs < 64; ofs <<= 1) {
        int t = __shfl_up(v, ofs);
        if (lane >= ofs) v += t;
    }
    return v;
}

// Bucket histogram (bucket = dst>>8), LDS-aggregated.
__global__ __launch_bounds__(256) void k_bhist(const int* __restrict__ dst,
                                               int* __restrict__ bucketCnt,
                                               int E, int NBUK) {
    __shared__ int h[NBUK_MAX];
    int tid = threadIdx.x;
    for (int i = tid; i < NBUK; i += 256) h[i] = 0;
    __syncthreads();
    for (int i = blockIdx.x * 256 + tid; i < E; i += gridDim.x * 256)
        atomicAdd(&h[dst[i] >> 8], 1);
    __syncthreads();
    for (int i = tid; i < NBUK; i += 256) {
        int c = h[i];
        if (c) atomicAdd(&bucketCnt[i], c);
    }
}

// One-wave exclusive scan of bucket counts -> bucketOff, gCursor.
__global__ void k_bscan(const int* __restrict__ bucketCnt,
                        int* __restrict__ bucketOff, int* __restrict__ gCursor,
                        int* __restrict__ rowptr, int N, int E, int NBUK) {
    int lane = threadIdx.x & 63;
    int running = 0;
    for (int base = 0; base < NBUK; base += 64) {
        int idx = base + lane;
        int v = (idx < NBUK) ? bucketCnt[idx] : 0;
        int incl = wave_incl_scan(v, lane);
        int excl = running + incl - v;
        if (idx < NBUK) { bucketOff[idx] = excl; gCursor[idx] = excl; }
        running += __shfl(incl, 63);
    }
    if (lane == 0) { bucketOff[NBUK] = running; rowptr[N] = E; }
}

// Bin edges into bucket-contiguous tmp. One global atomic per (block,bucket);
// packed word = (src<<8) | (dst&255).
__global__ __launch_bounds__(256) void k_bin(const int* __restrict__ src,
                                             const int* __restrict__ dst,
                                             int* __restrict__ gCursor,
                                             unsigned int* __restrict__ tmp,
                                             int E, int NBUK) {
    __shared__ int lcnt[NBUK_MAX];
    __shared__ int lcur[NBUK_MAX];
    int tid = threadIdx.x;
    int base = blockIdx.x * BIN_CHUNK;
    for (int i = tid; i < NBUK; i += 256) lcnt[i] = 0;
    __syncthreads();
    #pragma unroll
    for (int k = 0; k < BIN_CHUNK / 256; k++) {
        int i = base + tid + k * 256;
        if (i < E) atomicAdd(&lcnt[dst[i] >> 8], 1);
    }
    __syncthreads();
    for (int b = tid; b < NBUK; b += 256) {
        int c = lcnt[b];
        lcur[b] = c ? atomicAdd(&gCursor[b], c) : 0;
    }
    __syncthreads();
    #pragma unroll
    for (int k = 0; k < BIN_CHUNK / 256; k++) {
        int i = base + tid + k * 256;
        if (i < E) {
            int d = dst[i];
            int p = atomicAdd(&lcur[d >> 8], 1);
            tmp[p] = ((unsigned int)src[i] << 8) | (unsigned int)(d & 255);
        }
    }
}

// Exact CSR fill within a bucket; csr writes confined to block-owned window.
__global__ __launch_bounds__(256) void k_fill2(const unsigned int* __restrict__ tmp,
                                               const int* __restrict__ bucketOff,
                                               int* __restrict__ rowptr,
                                               int* __restrict__ csr, int N) {
    __shared__ int cnt[256];
    __shared__ int cur[256];
    __shared__ int wsum[4];
    int b = blockIdx.x, tid = threadIdx.x;
    int lane = tid & 63, wv = tid >> 6;
    int e0 = bucketOff[b], e1 = bucketOff[b + 1];
    cnt[tid] = 0;
    __syncthreads();
    for (int i = e0 + tid; i < e1; i += 256)
        atomicAdd(&cnt[tmp[i] & 255u], 1);
    __syncthreads();
    int v = cnt[tid];
    int incl = wave_incl_scan(v, lane);
    if (lane == 63) wsum[wv] = incl;
    __syncthreads();
    int woff = 0;
    for (int i = 0; i < wv; i++) woff += wsum[i];
    int excl = woff + incl - v;
    int node = b * 256 + tid;
    if (node < N) rowptr[node] = e0 + excl;
    cur[tid] = e0 + excl;
    __syncthreads();
    for (int i = e0 + tid; i < e1; i += 256) {
        unsigned int t = tmp[i];
        int p = atomicAdd(&cur[t & 255u], 1);
        csr[p] = (int)(t >> 8);
    }
}

// h1b[n][64](bf16) = [x[n]|topo[n]] @ W1 ; as1/ad1 from fp32 accumulators.
// Block = 64 nodes x 64 cols GEMM tile, K=136. W1 + xT staged in LDS.
__global__ __launch_bounds__(256) void k_xform1(const float* __restrict__ x,
                                                const float* __restrict__ topo,
                                                const float* __restrict__ W1,
                                                const float* __restrict__ asrc,
                                                const float* __restrict__ adst,
                                                ushort_t* __restrict__ h1b,
                                                float* __restrict__ as1,
                                                float* __restrict__ ad1, int N) {
    __shared__ float XT[136 * 64];  // XT[k][node]
    __shared__ float WS[136 * 64];  // WS[k][col]
    int tid = threadIdx.x;
    int n0 = blockIdx.x * 64;
    {   // stage W1: 8704 floats = 2176 float4 (once per block)
        const float4* W4 = (const float4*)W1;
        float4* WS4 = (float4*)WS;
        for (int i = tid; i < 2176; i += 256) WS4[i] = W4[i];
    }
    {   // stage x transposed: 64 nodes x 32 float4
        const float4* x4 = (const float4*)x;
        for (int i = tid; i < 2048; i += 256) {
            int node = i >> 5, k4 = i & 31;
            int gn = n0 + node; if (gn > N - 1) gn = N - 1;
            float4 v = x4[(size_t)gn * 32 + k4];
            int k = k4 * 4;
            XT[(k + 0) * 64 + node] = v.x;
            XT[(k + 1) * 64 + node] = v.y;
            XT[(k + 2) * 64 + node] = v.z;
            XT[(k + 3) * 64 + node] = v.w;
        }
        // topo rows 128..135: 64 nodes x 2 float4
        const float4* t4 = (const float4*)topo;
        if (tid < 128) {
            int node = tid >> 1, k4 = tid & 1;
            int gn = n0 + node; if (gn > N - 1) gn = N - 1;
            float4 v = t4[(size_t)gn * 2 + k4];
            int k = 128 + k4 * 4;
            XT[(k + 0) * 64 + node] = v.x;
            XT[(k + 1) * 64 + node] = v.y;
            XT[(k + 2) * 64 + node] = v.z;
            XT[(k + 3) * 64 + node] = v.w;
        }
    }
    __syncthreads();
    int ci = tid & 15, ni = tid >> 4;
    int nb = ni * 4, cb = ci * 4;
    float acc[16];
    #pragma unroll
    for (int i = 0; i < 16; i++) acc[i] = 0.f;
    #pragma unroll 4
    for (int k = 0; k < 136; k++) {
        float4 xv = *(const float4*)&XT[k * 64 + nb];
        float4 wv = *(const float4*)&WS[k * 64 + cb];
        acc[0]  = fmaf(xv.x, wv.x, acc[0]);  acc[1]  = fmaf(xv.x, wv.y, acc[1]);
        acc[2]  = fmaf(xv.x, wv.z, acc[2]);  acc[3]  = fmaf(xv.x, wv.w, acc[3]);
        acc[4]  = fmaf(xv.y, wv.x, acc[4]);  acc[5]  = fmaf(xv.y, wv.y, acc[5]);
        acc[6]  = fmaf(xv.y, wv.z, acc[6]);  acc[7]  = fmaf(xv.y, wv.w, acc[7]);
        acc[8]  = fmaf(xv.z, wv.x, acc[8]);  acc[9]  = fmaf(xv.z, wv.y, acc[9]);
        acc[10] = fmaf(xv.z, wv.z, acc[10]); acc[11] = fmaf(xv.z, wv.w, acc[11]);
        acc[12] = fmaf(xv.w, wv.x, acc[12]); acc[13] = fmaf(xv.w, wv.y, acc[13]);
        acc[14] = fmaf(xv.w, wv.z, acc[14]); acc[15] = fmaf(xv.w, wv.w, acc[15]);
    }
    int head = cb >> 3;  // cols cb..cb+3 lie in one head (cb multiple of 4)
    #pragma unroll
    for (int i = 0; i < 4; i++) {
        int n = n0 + nb + i;
        unsigned int p0 = f2bf(acc[i * 4 + 0]) | (f2bf(acc[i * 4 + 1]) << 16);
        unsigned int p1 = f2bf(acc[i * 4 + 2]) | (f2bf(acc[i * 4 + 3]) << 16);
        if (n < N) *(uint2*)&h1b[(size_t)n * 64 + cb] = make_uint2(p0, p1);
        float s = 0.f, d = 0.f;
        #pragma unroll
        for (int j = 0; j < 4; j++) {
            s = fmaf(acc[i * 4 + j], asrc[cb + j], s);
            d = fmaf(acc[i * 4 + j], adst[cb + j], d);
        }
        s += __shfl_xor(s, 1);  // combine the two half-head threads
        d += __shfl_xor(d, 1);
        if ((ci & 1) == 0 && n < N) {
            as1[n * 8 + head] = s;
            ad1[n * 8 + head] = d;
        }
    }
}

// Per-dst softmax-weighted aggregation over in-edges (+ implicit self loop).
// Edge loop unrolled x8. Weight trick: lane l computes (edge l>>3, head l&7)
// -> ONE wave-wide exp per 8 edges; per-edge weights via bpermute.
__global__ __launch_bounds__(256) void k_agg1(const ushort_t* __restrict__ h1b,
                                              const float* __restrict__ as1,
                                              const float* __restrict__ ad1,
                                              const float* __restrict__ b1,
                                              const int* __restrict__ rowptr,
                                              const int* __restrict__ csr,
                                              float* __restrict__ h2, int N) {
    int tid = threadIdx.x, lane = tid & 63;
    int n = blockIdx.x * 4 + (tid >> 6);
    if (n >= N) return;
    int myh = lane >> 3;
    float ad_d = ad1[n * 8 + myh];
    float adv = ad1[n * 8 + (lane & 7)];  // ad for head lane&7 (weight-lane view)
    float e0 = as1[n * 8 + myh] + ad_d;   // self loop
    float w0s = __expf(e0 >= 0.f ? e0 : 0.2f * e0);
    float acc0 = w0s * bf2f(h1b[(size_t)n * 64 + lane]), z0 = w0s;
    float acc1 = 0.f, z1 = 0.f, acc2 = 0.f, z2 = 0.f, acc3 = 0.f, z3 = 0.f;
    int j0 = rowptr[n], j1 = rowptr[n + 1];
    int j = j0;
    for (; j + 8 <= j1; j += 8) {
        int s0 = csr[j + 0], s1 = csr[j + 1], s2 = csr[j + 2], s3 = csr[j + 3];
        int s4 = csr[j + 4], s5 = csr[j + 5], s6 = csr[j + 6], s7 = csr[j + 7];
        // one wave-wide weight computation for all 8 edges x 8 heads
        int sjv = csr[j + (lane >> 3)];
        float av = as1[sjv * 8 + (lane & 7)];
        float qv = av + adv;
        float wvv = __expf(qv >= 0.f ? qv : 0.2f * qv);
        ushort_t u0 = h1b[(size_t)s0 * 64 + lane];
        ushort_t u1 = h1b[(size_t)s1 * 64 + lane];
        ushort_t u2 = h1b[(size_t)s2 * 64 + lane];
        ushort_t u3 = h1b[(size_t)s3 * 64 + lane];
        ushort_t u4 = h1b[(size_t)s4 * 64 + lane];
        ushort_t u5 = h1b[(size_t)s5 * 64 + lane];
        ushort_t u6 = h1b[(size_t)s6 * 64 + lane];
        ushort_t u7 = h1b[(size_t)s7 * 64 + lane];
        float w0 = __shfl(wvv, (0 << 3) | myh);
        float w1 = __shfl(wvv, (1 << 3) | myh);
        float w2 = __shfl(wvv, (2 << 3) | myh);
        float w3 = __shfl(wvv, (3 << 3) | myh);
        float w4 = __shfl(wvv, (4 << 3) | myh);
        float w5 = __shfl(wvv, (5 << 3) | myh);
        float w6 = __shfl(wvv, (6 << 3) | myh);
        float w7 = __shfl(wvv, (7 << 3) | myh);
        acc0 = fmaf(w0, bf2f(u0), acc0); z0 += w0;
        acc1 = fmaf(w1, bf2f(u1), acc1); z1 += w1;
        acc2 = fmaf(w2, bf2f(u2), acc2); z2 += w2;
        acc3 = fmaf(w3, bf2f(u3), acc3); z3 += w3;
        acc0 = fmaf(w4, bf2f(u4), acc0); z0 += w4;
        acc1 = fmaf(w5, bf2f(u5), acc1); z1 += w5;
        acc2 = fmaf(w6, bf2f(u6), acc2); z2 += w6;
        acc3 = fmaf(w7, bf2f(u7), acc3); z3 += w7;
    }
    for (; j < j1; ++j) {
        int s = csr[j];
        float e = as1[s * 8 + myh] + ad_d;
        float ww = __expf(e >= 0.f ? e : 0.2f * e);
        acc0 = fmaf(ww, bf2f(h1b[(size_t)s * 64 + lane]), acc0);
        z0 += ww;
    }
    float acc = (acc0 + acc1) + (acc2 + acc3);
    float z = (z0 + z1) + (z2 + z3);
    float v = acc / (z + 1e-16f) + b1[lane];
    h2[(size_t)n * 64 + lane] = v > 0.f ? v : (__expf(v) - 1.f);  // ELU
}

// gb[n][40](bf16) = h2[n] @ W2 ; as2/ad2 from fp32 accumulators.
// Block = 64 nodes x 40 cols GEMM tile, K=64.
__global__ __launch_bounds__(256) void k_xform2(const float* __restrict__ h2,
                                                const float* __restrict__ W2,
                                                const float* __restrict__ asrc2,
                                                const float* __restrict__ adst2,
                                                ushort_t* __restrict__ gb,
                                                float* __restrict__ as2,
                                                float* __restrict__ ad2, int N) {
    __shared__ float XT[64 * 64];  // h2T[k][node]
    __shared__ float WS[64 * 40];  // WS[k][col]
    int tid = threadIdx.x;
    int n0 = blockIdx.x * 64;
    {   // stage W2: 2560 floats = 640 float4
        const float4* W4 = (const float4*)W2;
        float4* WS4 = (float4*)WS;
        for (int i = tid; i < 640; i += 256) WS4[i] = W4[i];
    }
    {   // stage h2 transposed: 64 nodes x 16 float4
        const float4* h4 = (const float4*)h2;
        for (int i = tid; i < 1024; i += 256) {
            int node = i >> 4, k4 = i & 15;
            int gn = n0 + node; if (gn > N - 1) gn = N - 1;
            float4 v = h4[(size_t)gn * 16 + k4];
            int k = k4 * 4;
            XT[(k + 0) * 64 + node] = v.x;
            XT[(k + 1) * 64 + node] = v.y;
            XT[(k + 2) * 64 + node] = v.z;
            XT[(k + 3) * 64 + node] = v.w;
        }
    }
    __syncthreads();
    int ci = tid & 15, ni = tid >> 4;
    int nb = ni * 4, cb = ci * 4;
    float acc[16];
    #pragma unroll
    for (int i = 0; i < 16; i++) acc[i] = 0.f;
    if (ci < 10) {
        #pragma unroll 4
        for (int k = 0; k < 64; k++) {
            float4 xv = *(const float4*)&XT[k * 64 + nb];
            float4 wv = *(const float4*)&WS[k * 40 + cb];
            acc[0]  = fmaf(xv.x, wv.x, acc[0]);  acc[1]  = fmaf(xv.x, wv.y, acc[1]);
            acc[2]  = fmaf(xv.x, wv.z, acc[2]);  acc[3]  = fmaf(xv.x, wv.w, acc[3]);
            acc[4]  = fmaf(xv.y, wv.x, acc[4]);  acc[5]  = fmaf(xv.y, wv.y, acc[5]);
            acc[6]  = fmaf(xv.y, wv.z, acc[6]);  acc[7]  = fmaf(xv.y, wv.w, acc[7]);
            acc[8]  = fmaf(xv.z, wv.x, acc[8]);  acc[9]  = fmaf(xv.z, wv.y, acc[9]);
            acc[10] = fmaf(xv.z, wv.z, acc[10]); acc[11] = fmaf(xv.z, wv.w, acc[11]);
            acc[12] = fmaf(xv.w, wv.x, acc[12]); acc[13] = fmaf(xv.w, wv.y, acc[13]);
            acc[14] = fmaf(xv.w, wv.z, acc[14]); acc[15] = fmaf(xv.w, wv.w, acc[15]);
        }
    }
    #pragma unroll
    for (int i = 0; i < 4; i++) {
        int n = n0 + nb + i;
        if (ci < 10 && n < N) {
            unsigned int p0 = f2bf(acc[i * 4 + 0]) | (f2bf(acc[i * 4 + 1]) << 16);
            unsigned int p1 = f2bf(acc[i * 4 + 2]) | (f2bf(acc[i * 4 + 3]) << 16);
            *(uint2*)&gb[(size_t)n * 40 + cb] = make_uint2(p0, p1);
        }
        float s = 0.f, d = 0.f;
        if (ci < 10) {
            #pragma unroll
            for (int j = 0; j < 4; j++) {
                s = fmaf(acc[i * 4 + j], asrc2[cb + j], s);
                d = fmaf(acc[i * 4 + j], adst2[cb + j], d);
            }
        }
        // reduce over the 16-lane ci group (ci>=10 contribute 0)
        s += __shfl_xor(s, 1); s += __shfl_xor(s, 2);
        s += __shfl_xor(s, 4); s += __shfl_xor(s, 8);
        d += __shfl_xor(d, 1); d += __shfl_xor(d, 2);
        d += __shfl_xor(d, 4); d += __shfl_xor(d, 8);
        if (ci == 0 && n < N) { as2[n] = s; ad2[n] = d; }
    }
}

// Layer-2 aggregation + bias + log_softmax. Edge loop unrolled x8.
// Weight trick: lane l computes edge l&7's weight -> ONE exp per 8 edges.
__global__ __launch_bounds__(256) void k_agg2(const ushort_t* __restrict__ gb,
                                              const float* __restrict__ as2,
                                              const float* __restrict__ ad2,
                                              const float* __restrict__ b2,
                                              const int* __restrict__ rowptr,
                                              const int* __restrict__ csr,
                                              float* __restrict__ out, int N) {
    int tid = threadIdx.x, lane = tid & 63;
    int n = blockIdx.x * 4 + (tid >> 6);
    if (n >= N) return;
    int c = (lane < 40) ? lane : 0;
    float add = ad2[n];
    float e0 = as2[n] + add;
    float w0s = __expf(e0 >= 0.f ? e0 : 0.2f * e0);
    float acc0 = w0s * bf2f(gb[(size_t)n * 40 + c]), z0 = w0s;
    float acc1 = 0.f, z1 = 0.f, acc2 = 0.f, z2 = 0.f, acc3 = 0.f, z3 = 0.f;
    int j0 = rowptr[n], j1 = rowptr[n + 1];
    int j = j0;
    for (; j + 8 <= j1; j += 8) {
        int s0 = csr[j + 0], s1 = csr[j + 1], s2 = csr[j + 2], s3 = csr[j + 3];
        int s4 = csr[j + 4], s5 = csr[j + 5], s6 = csr[j + 6], s7 = csr[j + 7];
        // one wave-wide weight computation for all 8 edges
        int sjv = csr[j + (lane & 7)];
        float av = as2[sjv];
        float qv = av + add;
        float wvv = __expf(qv >= 0.f ? qv : 0.2f * qv);
        ushort_t u0 = gb[(size_t)s0 * 40 + c];
        ushort_t u1 = gb[(size_t)s1 * 40 + c];
        ushort_t u2 = gb[(size_t)s2 * 40 + c];
        ushort_t u3 = gb[(size_t)s3 * 40 + c];
        ushort_t u4 = gb[(size_t)s4 * 40 + c];
        ushort_t u5 = gb[(size_t)s5 * 40 + c];
        ushort_t u6 = gb[(size_t)s6 * 40 + c];
        ushort_t u7 = gb[(size_t)s7 * 40 + c];
        float w0 = __shfl(wvv, 0), w1 = __shfl(wvv, 1);
        float w2 = __shfl(wvv, 2), w3 = __shfl(wvv, 3);
        float w4 = __shfl(wvv, 4), w5 = __shfl(wvv, 5);
        float w6 = __shfl(wvv, 6), w7 = __shfl(wvv, 7);
        acc0 = fmaf(w0, bf2f(u0), acc0); z0 += w0;
        acc1 = fmaf(w1, bf2f(u1), acc1); z1 += w1;
        acc2 = fmaf(w2, bf2f(u2), acc2); z2 += w2;
        acc3 = fmaf(w3, bf2f(u3), acc3); z3 += w3;
        acc0 = fmaf(w4, bf2f(u4), acc0); z0 += w4;
        acc1 = fmaf(w5, bf2f(u5), acc1); z1 += w5;
        acc2 = fmaf(w6, bf2f(u6), acc2); z2 += w6;
        acc3 = fmaf(w7, bf2f(u7), acc3); z3 += w7;
    }
    for (; j < j1; ++j) {
        int s = csr[j];
        float e = as2[s] + add;
        float ww = __expf(e >= 0.f ? e : 0.2f * e);
        acc0 = fmaf(ww, bf2f(gb[(size_t)s * 40 + c]), acc0);
        z0 += ww;
    }
    float acc = (acc0 + acc1) + (acc2 + acc3);
    float z = (z0 + z1) + (z2 + z3);
    float logit = acc / (z + 1e-16f) + b2[c];
    float mv = (lane < 40) ? logit : -INFINITY;
    #pragma unroll
    for (int ofs = 1; ofs < 64; ofs <<= 1) mv = fmaxf(mv, __shfl_xor(mv, ofs));
    float ev = (lane < 40) ? __expf(logit - mv) : 0.f;
    #pragma unroll
    for (int ofs = 1; ofs < 64; ofs <<= 1) ev += __shfl_xor(ev, ofs);
    if (lane < 40) out[n * 40 + lane] = logit - mv - __logf(ev);
}

extern "C" void kernel_launch(void* const* d_in, const int* in_sizes, int n_in,
                              void* d_out, int out_size, void* d_ws, size_t ws_size,
                              hipStream_t stream) {
    const float* x    = (const float*)d_in[0];
    const float* topo = (const float*)d_in[1];
    const int*   ei   = (const int*)d_in[2];
    const float* W1   = (const float*)d_in[3];
    const float* a_s1 = (const float*)d_in[4];
    const float* a_d1 = (const float*)d_in[5];
    const float* b1   = (const float*)d_in[6];
    const float* W2   = (const float*)d_in[7];
    const float* a_s2 = (const float*)d_in[8];
    const float* a_d2 = (const float*)d_in[9];
    const float* b2   = (const float*)d_in[10];
    float* out = (float*)d_out;

    int N = in_sizes[0] / 128;
    int E = in_sizes[2] / 2;
    const int* esrc = ei;
    const int* edst = ei + E;
    int NBUK = (N + 255) / 256;

    char* ws = (char*)d_ws;
    size_t off = 0;
    auto alloc = [&](size_t bytes) -> void* {
        void* p = ws + off;
        off = (off + bytes + 255) & ~(size_t)255;
        return p;
    };
    ushort_t* h1b  = (ushort_t*)alloc((size_t)N * 64 * 2);
    float* as1     = (float*)alloc((size_t)N * 8 * 4);
    float* ad1     = (float*)alloc((size_t)N * 8 * 4);
    float* h2      = (float*)alloc((size_t)N * 64 * 4);
    ushort_t* gb   = (ushort_t*)alloc((size_t)N * 40 * 2);
    float* as2     = (float*)alloc((size_t)N * 4);
    float* ad2     = (float*)alloc((size_t)N * 4);
    int*   rowptr  = (int*)alloc((size_t)(N + 1) * 4);
    int*   csr     = (int*)alloc((size_t)E * 4);
    unsigned int* tmp = (unsigned int*)alloc((size_t)E * 4);
    int* bucketCnt = (int*)alloc((size_t)(NBUK + 1) * 4);
    int* bucketOff = (int*)alloc((size_t)(NBUK + 1) * 4);
    int* gCursor   = (int*)alloc((size_t)NBUK * 4);

    hipMemsetAsync(bucketCnt, 0, (size_t)(NBUK + 1) * 4, stream);
    k_bhist<<<256, 256, 0, stream>>>(edst, bucketCnt, E, NBUK);
    k_bscan<<<1, 64, 0, stream>>>(bucketCnt, bucketOff, gCursor, rowptr, N, E, NBUK);
    int nbin = (E + BIN_CHUNK - 1) / BIN_CHUNK;
    k_bin<<<nbin, 256, 0, stream>>>(esrc, edst, gCursor, tmp, E, NBUK);
    k_fill2<<<NBUK, 256, 0, stream>>>(tmp, bucketOff, rowptr, csr, N);

    int nbg = (N + 63) / 64;  // 64-node GEMM tiles
    int nb4 = (N + 3) / 4;    // 1 node/wave x 4 waves/block
    k_xform1<<<nbg, 256, 0, stream>>>(x, topo, W1, a_s1, a_d1, h1b, as1, ad1, N);
    k_agg1<<<nb4, 256, 0, stream>>>(h1b, as1, ad1, b1, rowptr, csr, h2, N);
    k_xform2<<<nbg, 256, 0, stream>>>(h2, W2, a_s2, a_d2, gb, as2, ad2, N);
    k_agg2<<<nb4, 256, 0, stream>>>(gb, as2, ad2, b2, rowptr, csr, out, N);
}

// Round 10
// 364.508 us; speedup vs baseline: 1.6350x; 1.0638x over previous
//
#include <hip/hip_runtime.h>
#include <math.h>

// ---------------------------------------------------------------------------
// TopoGAT: 2-layer GAT on MI355X.
// R3: CSR build via two-level binning (write-locality; ~1x writeback).
// R5: gather tables h1/g stored in bf16 (halves random-gather fabric bytes).
// R7: xform kernels as 2D register-tiled GEMM (W+xT in LDS, 4x4 thread tile).
// R8: one wave-wide exp per edge chunk (was 8-64x redundant).
// R9: multi-row gathers. agg1: 2 groups x 32 lanes, uint loads -> 2 full
//     128B rows per VMEM instruction; agg2: 3 groups x 20 lanes -> 3 x 80B
//     rows per instruction. csr via 1 coalesced load + bpermute. Chunked
//     (8/12 edges) with all gathers issued before compute (MLP preserved).
// ---------------------------------------------------------------------------

#define NBUK_MAX 512
#define BIN_CHUNK 4096

typedef unsigned short ushort_t;

__device__ inline unsigned int f2bf(float f) {  // RNE fp32->bf16
    unsigned int u = __float_as_uint(f);
    u += 0x7FFFu + ((u >> 16) & 1u);
    return u >> 16;
}
__device__ inline float bf2f(ushort_t b) {
    return __uint_as_float((unsigned int)b << 16);
}
__device__ inline float bf_lo(unsigned int u) {
    return __uint_as_float(u << 16);
}
__device__ inline float bf_hi(unsigned int u) {
    return __uint_as_float(u & 0xFFFF0000u);
}
__device__ inline float lrelu_exp(float q) {
    return __expf(q >= 0.f ? q : 0.2f * q);
}

__device__ inline int wave_incl_scan(int v, int lane) {
    #pragma unroll
    for (int ofs = 1; ofs < 64; ofs <<= 1) {
        int t = __shfl_up(v, ofs);
        if (lane >= ofs) v += t;
    }
    return v;
}

// Bucket histogram (bucket = dst>>8), LDS-aggregated.
__global__ __launch_bounds__(256) void k_bhist(const int* __restrict__ dst,
                                               int* __restrict__ bucketCnt,
                                               int E, int NBUK) {
    __shared__ int h[NBUK_MAX];
    int tid = threadIdx.x;
    for (int i = tid; i < NBUK; i += 256) h[i] = 0;
    __syncthreads();
    for (int i = blockIdx.x * 256 + tid; i < E; i += gridDim.x * 256)
        atomicAdd(&h[dst[i] >> 8], 1);
    __syncthreads();
    for (int i = tid; i < NBUK; i += 256) {
        int c = h[i];
        if (c) atomicAdd(&bucketCnt[i], c);
    }
}

// One-wave exclusive scan of bucket counts -> bucketOff, gCursor.
__global__ void k_bscan(const int* __restrict__ bucketCnt,
                        int* __restrict__ bucketOff, int* __restrict__ gCursor,
                        int* __restrict__ rowptr, int N, int E, int NBUK) {
    int lane = threadIdx.x & 63;
    int running = 0;
    for (int base = 0; base < NBUK; base += 64) {
        int idx = base + lane;
        int v = (idx < NBUK) ? bucketCnt[idx] : 0;
        int incl = wave_incl_scan(v, lane);
        int excl = running + incl - v;
        if (idx < NBUK) { bucketOff[idx] = excl; gCursor[idx] = excl; }
        running += __shfl(incl, 63);
    }
    if (lane == 0) { bucketOff[NBUK] = running; rowptr[N] = E; }
}

// Bin edges into bucket-contiguous tmp. One global atomic per (block,bucket);
// packed word = (src<<8) | (dst&255).
__global__ __launch_bounds__(256) void k_bin(const int* __restrict__ src,
                                             const int* __restrict__ dst,
                                             int* __restrict__ gCursor,
                                             unsigned int* __restrict__ tmp,
                                             int E, int NBUK) {
    __shared__ int lcnt[NBUK_MAX];
    __shared__ int lcur[NBUK_MAX];
    int tid = threadIdx.x;
    int base = blockIdx.x * BIN_CHUNK;
    for (int i = tid; i < NBUK; i += 256) lcnt[i] = 0;
    __syncthreads();
    #pragma unroll
    for (int k = 0; k < BIN_CHUNK / 256; k++) {
        int i = base + tid + k * 256;
        if (i < E) atomicAdd(&lcnt[dst[i] >> 8], 1);
    }
    __syncthreads();
    for (int b = tid; b < NBUK; b += 256) {
        int c = lcnt[b];
        lcur[b] = c ? atomicAdd(&gCursor[b], c) : 0;
    }
    __syncthreads();
    #pragma unroll
    for (int k = 0; k < BIN_CHUNK / 256; k++) {
        int i = base + tid + k * 256;
        if (i < E) {
            int d = dst[i];
            int p = atomicAdd(&lcur[d >> 8], 1);
            tmp[p] = ((unsigned int)src[i] << 8) | (unsigned int)(d & 255);
        }
    }
}

// Exact CSR fill within a bucket; csr writes confined to block-owned window.
__global__ __launch_bounds__(256) void k_fill2(const unsigned int* __restrict__ tmp,
                                               const int* __restrict__ bucketOff,
                                               int* __restrict__ rowptr,
                                               int* __restrict__ csr, int N) {
    __shared__ int cnt[256];
    __shared__ int cur[256];
    __shared__ int wsum[4];
    int b = blockIdx.x, tid = threadIdx.x;
    int lane = tid & 63, wv = tid >> 6;
    int e0 = bucketOff[b], e1 = bucketOff[b + 1];
    cnt[tid] = 0;
    __syncthreads();
    for (int i = e0 + tid; i < e1; i += 256)
        atomicAdd(&cnt[tmp[i] & 255u], 1);
    __syncthreads();
    int v = cnt[tid];
    int incl = wave_incl_scan(v, lane);
    if (lane == 63) wsum[wv] = incl;
    __syncthreads();
    int woff = 0;
    for (int i = 0; i < wv; i++) woff += wsum[i];
    int excl = woff + incl - v;
    int node = b * 256 + tid;
    if (node < N) rowptr[node] = e0 + excl;
    cur[tid] = e0 + excl;
    __syncthreads();
    for (int i = e0 + tid; i < e1; i += 256) {
        unsigned int t = tmp[i];
        int p = atomicAdd(&cur[t & 255u], 1);
        csr[p] = (int)(t >> 8);
    }
}

// h1b[n][64](bf16) = [x[n]|topo[n]] @ W1 ; as1/ad1 from fp32 accumulators.
// Block = 64 nodes x 64 cols GEMM tile, K=136. W1 + xT staged in LDS.
__global__ __launch_bounds__(256) void k_xform1(const float* __restrict__ x,
                                                const float* __restrict__ topo,
                                                const float* __restrict__ W1,
                                                const float* __restrict__ asrc,
                                                const float* __restrict__ adst,
                                                ushort_t* __restrict__ h1b,
                                                float* __restrict__ as1,
                                                float* __restrict__ ad1, int N) {
    __shared__ float XT[136 * 64];  // XT[k][node]
    __shared__ float WS[136 * 64];  // WS[k][col]
    int tid = threadIdx.x;
    int n0 = blockIdx.x * 64;
    {   // stage W1: 8704 floats = 2176 float4 (once per block)
        const float4* W4 = (const float4*)W1;
        float4* WS4 = (float4*)WS;
        for (int i = tid; i < 2176; i += 256) WS4[i] = W4[i];
    }
    {   // stage x transposed: 64 nodes x 32 float4
        const float4* x4 = (const float4*)x;
        for (int i = tid; i < 2048; i += 256) {
            int node = i >> 5, k4 = i & 31;
            int gn = n0 + node; if (gn > N - 1) gn = N - 1;
            float4 v = x4[(size_t)gn * 32 + k4];
            int k = k4 * 4;
            XT[(k + 0) * 64 + node] = v.x;
            XT[(k + 1) * 64 + node] = v.y;
            XT[(k + 2) * 64 + node] = v.z;
            XT[(k + 3) * 64 + node] = v.w;
        }
        // topo rows 128..135: 64 nodes x 2 float4
        const float4* t4 = (const float4*)topo;
        if (tid < 128) {
            int node = tid >> 1, k4 = tid & 1;
            int gn = n0 + node; if (gn > N - 1) gn = N - 1;
            float4 v = t4[(size_t)gn * 2 + k4];
            int k = 128 + k4 * 4;
            XT[(k + 0) * 64 + node] = v.x;
            XT[(k + 1) * 64 + node] = v.y;
            XT[(k + 2) * 64 + node] = v.z;
            XT[(k + 3) * 64 + node] = v.w;
        }
    }
    __syncthreads();
    int ci = tid & 15, ni = tid >> 4;
    int nb = ni * 4, cb = ci * 4;
    float acc[16];
    #pragma unroll
    for (int i = 0; i < 16; i++) acc[i] = 0.f;
    #pragma unroll 4
    for (int k = 0; k < 136; k++) {
        float4 xv = *(const float4*)&XT[k * 64 + nb];
        float4 wv = *(const float4*)&WS[k * 64 + cb];
        acc[0]  = fmaf(xv.x, wv.x, acc[0]);  acc[1]  = fmaf(xv.x, wv.y, acc[1]);
        acc[2]  = fmaf(xv.x, wv.z, acc[2]);  acc[3]  = fmaf(xv.x, wv.w, acc[3]);
        acc[4]  = fmaf(xv.y, wv.x, acc[4]);  acc[5]  = fmaf(xv.y, wv.y, acc[5]);
        acc[6]  = fmaf(xv.y, wv.z, acc[6]);  acc[7]  = fmaf(xv.y, wv.w, acc[7]);
        acc[8]  = fmaf(xv.z, wv.x, acc[8]);  acc[9]  = fmaf(xv.z, wv.y, acc[9]);
        acc[10] = fmaf(xv.z, wv.z, acc[10]); acc[11] = fmaf(xv.z, wv.w, acc[11]);
        acc[12] = fmaf(xv.w, wv.x, acc[12]); acc[13] = fmaf(xv.w, wv.y, acc[13]);
        acc[14] = fmaf(xv.w, wv.z, acc[14]); acc[15] = fmaf(xv.w, wv.w, acc[15]);
    }
    int head = cb >> 3;  // cols cb..cb+3 lie in one head (cb multiple of 4)
    #pragma unroll
    for (int i = 0; i < 4; i++) {
        int n = n0 + nb + i;
        unsigned int p0 = f2bf(acc[i * 4 + 0]) | (f2bf(acc[i * 4 + 1]) << 16);
        unsigned int p1 = f2bf(acc[i * 4 + 2]) | (f2bf(acc[i * 4 + 3]) << 16);
        if (n < N) *(uint2*)&h1b[(size_t)n * 64 + cb] = make_uint2(p0, p1);
        float s = 0.f, d = 0.f;
        #pragma unroll
        for (int j = 0; j < 4; j++) {
            s = fmaf(acc[i * 4 + j], asrc[cb + j], s);
            d = fmaf(acc[i * 4 + j], adst[cb + j], d);
        }
        s += __shfl_xor(s, 1);  // combine the two half-head threads
        d += __shfl_xor(d, 1);
        if ((ci & 1) == 0 && n < N) {
            as1[n * 8 + head] = s;
            ad1[n * 8 + head] = d;
        }
    }
}

// Per-dst softmax-weighted aggregation, layer 1 (+ implicit self loop).
// 2 groups x 32 lanes: lane (g=l>>5, p=l&31) handles cols 2p,2p+1 of every
// 2nd edge -> one uint gather instruction fetches TWO full 128B rows.
__global__ __launch_bounds__(256) void k_agg1(const ushort_t* __restrict__ h1b,
                                              const float* __restrict__ as1,
                                              const float* __restrict__ ad1,
                                              const float* __restrict__ b1,
                                              const int* __restrict__ rowptr,
                                              const int* __restrict__ csr,
                                              float* __restrict__ h2, int N) {
    int tid = threadIdx.x, lane = tid & 63;
    int n = blockIdx.x * 4 + (tid >> 6);
    if (n >= N) return;
    int g = lane >> 5, p = lane & 31;
    int c0 = 2 * p;
    int h = p >> 2;  // head of cols c0, c0+1
    float ad_dl = ad1[n * 8 + h];
    float acc0 = 0.f, acc1 = 0.f, zl = 0.f;
    {   // self loop (group 0 only)
        float e0 = as1[n * 8 + h] + ad_dl;
        float w = lrelu_exp(e0);
        if (g == 0) {
            unsigned int u = *(const unsigned int*)&h1b[(size_t)n * 64 + c0];
            acc0 = w * bf_lo(u); acc1 = w * bf_hi(u); zl = w;
        }
    }
    int j0 = rowptr[n], j1 = rowptr[n + 1];
    int j = j0;
    for (; j + 8 <= j1; j += 8) {
        int cv = csr[j + (lane & 7)];           // coalesced, then bpermute
        int s0 = __shfl(cv, 0 + g);
        int s1 = __shfl(cv, 2 + g);
        int s2 = __shfl(cv, 4 + g);
        int s3 = __shfl(cv, 6 + g);
        float a0 = as1[s0 * 8 + h];
        float a1 = as1[s1 * 8 + h];
        float a2 = as1[s2 * 8 + h];
        float a3 = as1[s3 * 8 + h];
        unsigned int u0 = *(const unsigned int*)&h1b[(size_t)s0 * 64 + c0];
        unsigned int u1 = *(const unsigned int*)&h1b[(size_t)s1 * 64 + c0];
        unsigned int u2 = *(const unsigned int*)&h1b[(size_t)s2 * 64 + c0];
        unsigned int u3 = *(const unsigned int*)&h1b[(size_t)s3 * 64 + c0];
        float w0 = lrelu_exp(a0 + ad_dl);
        float w1 = lrelu_exp(a1 + ad_dl);
        float w2 = lrelu_exp(a2 + ad_dl);
        float w3 = lrelu_exp(a3 + ad_dl);
        acc0 = fmaf(w0, bf_lo(u0), acc0); acc1 = fmaf(w0, bf_hi(u0), acc1); zl += w0;
        acc0 = fmaf(w1, bf_lo(u1), acc0); acc1 = fmaf(w1, bf_hi(u1), acc1); zl += w1;
        acc0 = fmaf(w2, bf_lo(u2), acc0); acc1 = fmaf(w2, bf_hi(u2), acc1); zl += w2;
        acc0 = fmaf(w3, bf_lo(u3), acc0); acc1 = fmaf(w3, bf_hi(u3), acc1); zl += w3;
    }
    for (; j + 2 <= j1; j += 2) {
        int s = csr[j + g];
        float a = as1[s * 8 + h];
        unsigned int u = *(const unsigned int*)&h1b[(size_t)s * 64 + c0];
        float w = lrelu_exp(a + ad_dl);
        acc0 = fmaf(w, bf_lo(u), acc0); acc1 = fmaf(w, bf_hi(u), acc1); zl += w;
    }
    for (; j < j1; ++j) {  // last odd edge: group 0 only
        int s = csr[j];
        float a = as1[s * 8 + h];
        unsigned int u = *(const unsigned int*)&h1b[(size_t)s * 64 + c0];
        float w = (g == 0) ? lrelu_exp(a + ad_dl) : 0.f;
        acc0 = fmaf(w, bf_lo(u), acc0); acc1 = fmaf(w, bf_hi(u), acc1); zl += w;
    }
    float A0 = acc0 + __shfl_xor(acc0, 32);
    float A1 = acc1 + __shfl_xor(acc1, 32);
    float Z  = zl + __shfl_xor(zl, 32);
    if (g == 0) {
        float inv = 1.f / (Z + 1e-16f);
        float v0 = A0 * inv + b1[c0];
        float v1 = A1 * inv + b1[c0 + 1];
        v0 = v0 > 0.f ? v0 : (__expf(v0) - 1.f);
        v1 = v1 > 0.f ? v1 : (__expf(v1) - 1.f);
        *(float2*)&h2[(size_t)n * 64 + c0] = make_float2(v0, v1);
    }
}

// gb[n][40](bf16) = h2[n] @ W2 ; as2/ad2 from fp32 accumulators.
// Block = 64 nodes x 40 cols GEMM tile, K=64.
__global__ __launch_bounds__(256) void k_xform2(const float* __restrict__ h2,
                                                const float* __restrict__ W2,
                                                const float* __restrict__ asrc2,
                                                const float* __restrict__ adst2,
                                                ushort_t* __restrict__ gb,
                                                float* __restrict__ as2,
                                                float* __restrict__ ad2, int N) {
    __shared__ float XT[64 * 64];  // h2T[k][node]
    __shared__ float WS[64 * 40];  // WS[k][col]
    int tid = threadIdx.x;
    int n0 = blockIdx.x * 64;
    {   // stage W2: 2560 floats = 640 float4
        const float4* W4 = (const float4*)W2;
        float4* WS4 = (float4*)WS;
        for (int i = tid; i < 640; i += 256) WS4[i] = W4[i];
    }
    {   // stage h2 transposed: 64 nodes x 16 float4
        const float4* h4 = (const float4*)h2;
        for (int i = tid; i < 1024; i += 256) {
            int node = i >> 4, k4 = i & 15;
            int gn = n0 + node; if (gn > N - 1) gn = N - 1;
            float4 v = h4[(size_t)gn * 16 + k4];
            int k = k4 * 4;
            XT[(k + 0) * 64 + node] = v.x;
            XT[(k + 1) * 64 + node] = v.y;
            XT[(k + 2) * 64 + node] = v.z;
            XT[(k + 3) * 64 + node] = v.w;
        }
    }
    __syncthreads();
    int ci = tid & 15, ni = tid >> 4;
    int nb = ni * 4, cb = ci * 4;
    float acc[16];
    #pragma unroll
    for (int i = 0; i < 16; i++) acc[i] = 0.f;
    if (ci < 10) {
        #pragma unroll 4
        for (int k = 0; k < 64; k++) {
            float4 xv = *(const float4*)&XT[k * 64 + nb];
            float4 wv = *(const float4*)&WS[k * 40 + cb];
            acc[0]  = fmaf(xv.x, wv.x, acc[0]);  acc[1]  = fmaf(xv.x, wv.y, acc[1]);
            acc[2]  = fmaf(xv.x, wv.z, acc[2]);  acc[3]  = fmaf(xv.x, wv.w, acc[3]);
            acc[4]  = fmaf(xv.y, wv.x, acc[4]);  acc[5]  = fmaf(xv.y, wv.y, acc[5]);
            acc[6]  = fmaf(xv.y, wv.z, acc[6]);  acc[7]  = fmaf(xv.y, wv.w, acc[7]);
            acc[8]  = fmaf(xv.z, wv.x, acc[8]);  acc[9]  = fmaf(xv.z, wv.y, acc[9]);
            acc[10] = fmaf(xv.z, wv.z, acc[10]); acc[11] = fmaf(xv.z, wv.w, acc[11]);
            acc[12] = fmaf(xv.w, wv.x, acc[12]); acc[13] = fmaf(xv.w, wv.y, acc[13]);
            acc[14] = fmaf(xv.w, wv.z, acc[14]); acc[15] = fmaf(xv.w, wv.w, acc[15]);
        }
    }
    #pragma unroll
    for (int i = 0; i < 4; i++) {
        int n = n0 + nb + i;
        if (ci < 10 && n < N) {
            unsigned int p0 = f2bf(acc[i * 4 + 0]) | (f2bf(acc[i * 4 + 1]) << 16);
            unsigned int p1 = f2bf(acc[i * 4 + 2]) | (f2bf(acc[i * 4 + 3]) << 16);
            *(uint2*)&gb[(size_t)n * 40 + cb] = make_uint2(p0, p1);
        }
        float s = 0.f, d = 0.f;
        if (ci < 10) {
            #pragma unroll
            for (int j = 0; j < 4; j++) {
                s = fmaf(acc[i * 4 + j], asrc2[cb + j], s);
                d = fmaf(acc[i * 4 + j], adst2[cb + j], d);
            }
        }
        // reduce over the 16-lane ci group (ci>=10 contribute 0)
        s += __shfl_xor(s, 1); s += __shfl_xor(s, 2);
        s += __shfl_xor(s, 4); s += __shfl_xor(s, 8);
        d += __shfl_xor(d, 1); d += __shfl_xor(d, 2);
        d += __shfl_xor(d, 4); d += __shfl_xor(d, 8);
        if (ci == 0 && n < N) { as2[n] = s; ad2[n] = d; }
    }
}

// Layer-2 aggregation + bias + log_softmax.
// 3 groups x 20 lanes: lane (g=l/20, p=l%20) handles cols 2p,2p+1 of every
// 3rd edge -> one uint gather instruction fetches THREE 80B rows.
__global__ __launch_bounds__(256) void k_agg2(const ushort_t* __restrict__ gb,
                                              const float* __restrict__ as2,
                                              const float* __restrict__ ad2,
                                              const float* __restrict__ b2,
                                              const int* __restrict__ rowptr,
                                              const int* __restrict__ csr,
                                              float* __restrict__ out, int N) {
    int tid = threadIdx.x, lane = tid & 63;
    int n = blockIdx.x * 4 + (tid >> 6);
    if (n >= N) return;
    int g = lane / 20, p = lane % 20;  // g==3 for lanes 60-63 (results unread)
    int c0 = 2 * p;
    float add = ad2[n];
    float acc0 = 0.f, acc1 = 0.f, zl = 0.f;
    {   // self loop (group 0 only)
        float e0 = as2[n] + add;
        float w = lrelu_exp(e0);
        if (g == 0) {
            unsigned int u = *(const unsigned int*)&gb[(size_t)n * 40 + c0];
            acc0 = w * bf_lo(u); acc1 = w * bf_hi(u); zl = w;
        }
    }
    int j0 = rowptr[n], j1 = rowptr[n + 1];
    int j = j0;
    int gi0 = (0 + g) < 12 ? (0 + g) : 11;   // clamp for g==3 lanes
    int gi1 = (3 + g) < 12 ? (3 + g) : 11;
    int gi2 = (6 + g) < 12 ? (6 + g) : 11;
    int gi3 = (9 + g) < 12 ? (9 + g) : 11;
    for (; j + 12 <= j1; j += 12) {
        int cv = csr[j + (lane % 12)];   // coalesced, then bpermute
        int s0 = __shfl(cv, gi0);
        int s1 = __shfl(cv, gi1);
        int s2 = __shfl(cv, gi2);
        int s3 = __shfl(cv, gi3);
        float a0 = as2[s0], a1 = as2[s1], a2 = as2[s2], a3 = as2[s3];
        unsigned int u0 = *(const unsigned int*)&gb[(size_t)s0 * 40 + c0];
        unsigned int u1 = *(const unsigned int*)&gb[(size_t)s1 * 40 + c0];
        unsigned int u2 = *(const unsigned int*)&gb[(size_t)s2 * 40 + c0];
        unsigned int u3 = *(const unsigned int*)&gb[(size_t)s3 * 40 + c0];
        float w0 = lrelu_exp(a0 + add);
        float w1 = lrelu_exp(a1 + add);
        float w2 = lrelu_exp(a2 + add);
        float w3 = lrelu_exp(a3 + add);
        acc0 = fmaf(w0, bf_lo(u0), acc0); acc1 = fmaf(w0, bf_hi(u0), acc1); zl += w0;
        acc0 = fmaf(w1, bf_lo(u1), acc0); acc1 = fmaf(w1, bf_hi(u1), acc1); zl += w1;
        acc0 = fmaf(w2, bf_lo(u2), acc0); acc1 = fmaf(w2, bf_hi(u2), acc1); zl += w2;
        acc0 = fmaf(w3, bf_lo(u3), acc0); acc1 = fmaf(w3, bf_hi(u3), acc1); zl += w3;
    }
    for (; j + 3 <= j1; j += 3) {
        int s = csr[j + (g < 3 ? g : 2)];
        float a = as2[s];
        unsigned int u = *(const unsigned int*)&gb[(size_t)s * 40 + c0];
        float w = lrelu_exp(a + add);
        acc0 = fmaf(w, bf_lo(u), acc0); acc1 = fmaf(w, bf_hi(u), acc1); zl += w;
    }
    for (; j < j1; ++j) {  // remaining 1-2 edges: group 0 only
        int s = csr[j];
        float a = as2[s];
        unsigned int u = *(const unsigned int*)&gb[(size_t)s * 40 + c0];
        float w = (g == 0) ? lrelu_exp(a + add) : 0.f;
        acc0 = fmaf(w, bf_lo(u), acc0); acc1 = fmaf(w, bf_hi(u), acc1); zl += w;
    }
    // combine the 3 groups (valid at lanes 0..19)
    float A0 = acc0 + __shfl(acc0, (lane + 20) & 63) + __shfl(acc0, (lane + 40) & 63);
    float A1 = acc1 + __shfl(acc1, (lane + 20) & 63) + __shfl(acc1, (lane + 40) & 63);
    float Z  = zl + __shfl(zl, (lane + 20) & 63) + __shfl(zl, (lane + 40) & 63);
    float l0 = 0.f, l1 = 0.f;
    bool active = (lane < 20);
    if (active) {
        float inv = 1.f / (Z + 1e-16f);
        l0 = A0 * inv + b2[c0];
        l1 = A1 * inv + b2[c0 + 1];
    }
    // masked 32-lane butterfly for max and sum-exp over the 40 logits
    float mv = active ? fmaxf(l0, l1) : -INFINITY;
    #pragma unroll
    for (int ofs = 1; ofs < 32; ofs <<= 1) mv = fmaxf(mv, __shfl_xor(mv, ofs));
    float ev = active ? (__expf(l0 - mv) + __expf(l1 - mv)) : 0.f;
    #pragma unroll
    for (int ofs = 1; ofs < 32; ofs <<= 1) ev += __shfl_xor(ev, ofs);
    if (active) {
        float ls = mv + __logf(ev);
        *(float2*)&out[(size_t)n * 40 + c0] = make_float2(l0 - ls, l1 - ls);
    }
}

extern "C" void kernel_launch(void* const* d_in, const int* in_sizes, int n_in,
                              void* d_out, int out_size, void* d_ws, size_t ws_size,
                              hipStream_t stream) {
    const float* x    = (const float*)d_in[0];
    const float* topo = (const float*)d_in[1];
    const int*   ei   = (const int*)d_in[2];
    const float* W1   = (const float*)d_in[3];
    const float* a_s1 = (const float*)d_in[4];
    const float* a_d1 = (const float*)d_in[5];
    const float* b1   = (const float*)d_in[6];
    const float* W2   = (const float*)d_in[7];
    const float* a_s2 = (const float*)d_in[8];
    const float* a_d2 = (const float*)d_in[9];
    const float* b2   = (const float*)d_in[10];
    float* out = (float*)d_out;

    int N = in_sizes[0] / 128;
    int E = in_sizes[2] / 2;
    const int* esrc = ei;
    const int* edst = ei + E;
    int NBUK = (N + 255) / 256;

    char* ws = (char*)d_ws;
    size_t off = 0;
    auto alloc = [&](size_t bytes) -> void* {
        void* p = ws + off;
        off = (off + bytes + 255) & ~(size_t)255;
        return p;
    };
    ushort_t* h1b  = (ushort_t*)alloc((size_t)N * 64 * 2);
    float* as1     = (float*)alloc((size_t)N * 8 * 4);
    float* ad1     = (float*)alloc((size_t)N * 8 * 4);
    float* h2      = (float*)alloc((size_t)N * 64 * 4);
    ushort_t* gb   = (ushort_t*)alloc((size_t)N * 40 * 2);
    float* as2     = (float*)alloc((size_t)N * 4);
    float* ad2     = (float*)alloc((size_t)N * 4);
    int*   rowptr  = (int*)alloc((size_t)(N + 1) * 4);
    int*   csr     = (int*)alloc((size_t)E * 4);
    unsigned int* tmp = (unsigned int*)alloc((size_t)E * 4);
    int* bucketCnt = (int*)alloc((size_t)(NBUK + 1) * 4);
    int* bucketOff = (int*)alloc((size_t)(NBUK + 1) * 4);
    int* gCursor   = (int*)alloc((size_t)NBUK * 4);

    hipMemsetAsync(bucketCnt, 0, (size_t)(NBUK + 1) * 4, stream);
    k_bhist<<<256, 256, 0, stream>>>(edst, bucketCnt, E, NBUK);
    k_bscan<<<1, 64, 0, stream>>>(bucketCnt, bucketOff, gCursor, rowptr, N, E, NBUK);
    int nbin = (E + BIN_CHUNK - 1) / BIN_CHUNK;
    k_bin<<<nbin, 256, 0, stream>>>(esrc, edst, gCursor, tmp, E, NBUK);
    k_fill2<<<NBUK, 256, 0, stream>>>(tmp, bucketOff, rowptr, csr, N);

    int nbg = (N + 63) / 64;  // 64-node GEMM tiles
    int nb4 = (N + 3) / 4;    // 1 node/wave x 4 waves/block
    k_xform1<<<nbg, 256, 0, stream>>>(x, topo, W1, a_s1, a_d1, h1b, as1, ad1, N);
    k_agg1<<<nb4, 256, 0, stream>>>(h1b, as1, ad1, b1, rowptr, csr, h2, N);
    k_xform2<<<nbg, 256, 0, stream>>>(h2, W2, a_s2, a_d2, gb, as2, ad2, N);
    k_agg2<<<nb4, 256, 0, stream>>>(gb, as2, ad2, b2, rowptr, csr, out, N);
}